// Round 11
// baseline (330.430 us; speedup 1.0000x reference)
//
#include <hip/hip_runtime.h>
#include <hip/hip_bf16.h>
#include <math.h>

#define Bb 2
#define Ss 2048
#define Ee 1024
#define Hh 16
#define HDd 64
#define NEG_INF_F -1000000000.0f

typedef __attribute__((ext_vector_type(8))) short bfrag;     // 8 bf16
typedef __attribute__((ext_vector_type(4))) float ffrag;     // 16x16 C/D
typedef __attribute__((ext_vector_type(16))) float ffrag16;  // 32x32 C/D
typedef __attribute__((ext_vector_type(8))) unsigned short us8;

#define C1F 0.1803368801f  /* 0.125 * log2(e) — folded into Q at gemm_qkv */

// ---- bf16 helpers ----------------------------------------------------------
__device__ __forceinline__ unsigned short f2bf(float x) {
  unsigned u = __float_as_uint(x);
  u += 0x7fffu + ((u >> 16) & 1u);
  return (unsigned short)(u >> 16);
}
__device__ __forceinline__ float bf2f(unsigned short h) {
  return __uint_as_float(((unsigned)h) << 16);
}

__device__ __forceinline__ void async_copy16(void* lds, const void* g) {
  __builtin_amdgcn_global_load_lds(
      (const __attribute__((address_space(1))) unsigned int*)g,
      (__attribute__((address_space(3))) unsigned int*)lds, 16, 0, 0);
}

// ---------------------------------------------------------------------------
// Fused split pass: x (4M) -> hi only; Wqkv (3M), Wout (1M) -> hi/lo.
// ---------------------------------------------------------------------------
__global__ __launch_bounds__(256) void split_all(
    const float* __restrict__ x, unsigned short* __restrict__ xh,
    const float* __restrict__ wq, unsigned short* __restrict__ wqh,
    unsigned short* __restrict__ wql,
    const float* __restrict__ wo, unsigned short* __restrict__ woh,
    unsigned short* __restrict__ wol) {
  int bid = blockIdx.x;
  const float* in;
  unsigned short *hi, *lo;
  if (bid < 4096) { in = x; hi = xh; lo = nullptr; }
  else if (bid < 7168) { bid -= 4096; in = wq; hi = wqh; lo = wql; }
  else { bid -= 7168; in = wo; hi = woh; lo = wol; }
  const int idx = (bid * 256 + threadIdx.x) * 4;
  const float4 v = *(const float4*)(in + idx);
  unsigned short h0 = f2bf(v.x), h1 = f2bf(v.y), h2 = f2bf(v.z), h3 = f2bf(v.w);
  ushort4 hv = {h0, h1, h2, h3};
  *(ushort4*)(hi + idx) = hv;
  if (lo) {
    ushort4 lv = {f2bf(v.x - bf2f(h0)), f2bf(v.y - bf2f(h1)),
                  f2bf(v.z - bf2f(h2)), f2bf(v.w - bf2f(h3))};
    *(ushort4*)(lo + idx) = lv;
  }
}

// ---------------------------------------------------------------------------
// LDS slot map (rows of 32 bf16 = 4 x 16B chunks):
// slot(row,q) = (row>>1)*8 + ((((row&1)*4)|q) ^ ((row>>1)&7)).
// ---------------------------------------------------------------------------
__device__ __forceinline__ int gemm_slot(int row, int q) {
  return (row >> 1) * 8 + ((((row & 1) * 4) | q) ^ ((row >> 1) & 7));
}
__device__ __forceinline__ int slot_src_off(int slot, int ld) {
  const int dr = slot >> 3;
  const int idx8 = (slot & 7) ^ (dr & 7);
  const int row = dr * 2 + (idx8 >> 2);
  const int q = idx8 & 3;
  return row * ld + q * 8;
}

// ---------------------------------------------------------------------------
// QKV GEMM, 32x32x16 core: C = xh * (Wh + Wl)^T + bias (2 MFMAs/product).
// 128x128 tile. Epilogue: Q single bf16 pre-scaled by C1F -> [bh][s][64];
// K hi/lo -> [bh][s][64]; V single bf16 transposed -> [bh][d][s].
// ---------------------------------------------------------------------------
__global__ __launch_bounds__(256) void gemm_qkv(
    const unsigned short* __restrict__ Ah,
    const unsigned short* __restrict__ Bh, const unsigned short* __restrict__ Bl,
    const float* __restrict__ bias,
    unsigned short* __restrict__ q_h,
    unsigned short* __restrict__ k_h, unsigned short* __restrict__ k_l,
    unsigned short* __restrict__ vt_h) {
  __shared__ unsigned short sm[3 * 4096];
  const int tid = threadIdx.x;
  const int lane = tid & 63;
  const int w = tid >> 6;
  const int wm = w >> 1;
  const int wn = w & 1;
  const int l31 = lane & 31;
  const int e = lane >> 5;
  const int m0 = blockIdx.x * 128;
  const int n0 = blockIdx.y * 128;

  int coff[2], ldsb[2];
#pragma unroll
  for (int u = 0; u < 2; ++u) {
    const int slot = w * 128 + u * 64 + lane;
    coff[u] = slot_src_off(slot, 1024);
    ldsb[u] = (w * 128 + u * 64) * 8;
  }
  const unsigned short* srcs[3] = {
      Ah + (size_t)m0 * 1024, Bh + (size_t)n0 * 1024, Bl + (size_t)n0 * 1024};

  ffrag16 acc[2][2];
#pragma unroll
  for (int i = 0; i < 2; ++i)
#pragma unroll
    for (int j = 0; j < 2; ++j) acc[i][j] = (ffrag16)0.f;

  int ca[2][2], cb[2][2];
#pragma unroll
  for (int t = 0; t < 2; ++t)
#pragma unroll
    for (int h2 = 0; h2 < 2; ++h2) {
      ca[t][h2] = gemm_slot(wm * 64 + t * 32 + l31, h2 * 2 + e) * 8;
      cb[t][h2] = gemm_slot(wn * 64 + t * 32 + l31, h2 * 2 + e) * 8;
    }

  for (int k0 = 0; k0 < 1024; k0 += 32) {
    __syncthreads();
#pragma unroll
    for (int t = 0; t < 3; ++t)
#pragma unroll
      for (int u = 0; u < 2; ++u)
        async_copy16(&sm[t * 4096 + ldsb[u]], srcs[t] + coff[u] + k0);
    __syncthreads();

    bfrag ah[2][2], bhf[2][2], blf[2][2];
#pragma unroll
    for (int t = 0; t < 2; ++t)
#pragma unroll
      for (int h2 = 0; h2 < 2; ++h2) {
        ah[t][h2] = *(const bfrag*)&sm[0 * 4096 + ca[t][h2]];
        bhf[t][h2] = *(const bfrag*)&sm[1 * 4096 + cb[t][h2]];
        blf[t][h2] = *(const bfrag*)&sm[2 * 4096 + cb[t][h2]];
      }
#pragma unroll
    for (int mt = 0; mt < 2; ++mt)
#pragma unroll
      for (int nt = 0; nt < 2; ++nt)
#pragma unroll
        for (int h2 = 0; h2 < 2; ++h2) {
          acc[mt][nt] = __builtin_amdgcn_mfma_f32_32x32x16_bf16(
              ah[mt][h2], bhf[nt][h2], acc[mt][nt], 0, 0, 0);
          acc[mt][nt] = __builtin_amdgcn_mfma_f32_32x32x16_bf16(
              ah[mt][h2], blf[nt][h2], acc[mt][nt], 0, 0, 0);
        }
  }

#pragma unroll
  for (int nt = 0; nt < 2; ++nt) {
    const int n = n0 + wn * 64 + nt * 32 + l31;
    const float bv = bias[n];
    const int h = n / 192;
    const int c = n - h * 192;
    const int d = c & 63;
#pragma unroll
    for (int mt = 0; mt < 2; ++mt) {
      if (c >= 128) {
#pragma unroll
        for (int g = 0; g < 4; ++g) {
          const int m = m0 + wm * 64 + mt * 32 + g * 8 + e * 4;
          const int bidx = m >> 11;
          const int s = m & 2047;
          ushort4 hv4;
          unsigned short* ph = (unsigned short*)&hv4;
#pragma unroll
          for (int r = 0; r < 4; ++r)
            ph[r] = f2bf(acc[mt][nt][g * 4 + r] + bv);
          const size_t off =
              (size_t)(bidx * 16 + h) * (64 * 2048) + (size_t)d * 2048 + s;
          *(ushort4*)(vt_h + off) = hv4;
        }
      } else if (c < 64) {
#pragma unroll
        for (int g = 0; g < 4; ++g)
#pragma unroll
          for (int r = 0; r < 4; ++r) {
            const int m = m0 + wm * 64 + mt * 32 + g * 8 + e * 4 + r;
            const int bidx = m >> 11;
            const int s = m & 2047;
            const size_t off =
                (size_t)(bidx * 16 + h) * (2048 * 64) + (size_t)s * 64 + d;
            q_h[off] = f2bf((acc[mt][nt][g * 4 + r] + bv) * C1F);
          }
      } else {
#pragma unroll
        for (int g = 0; g < 4; ++g)
#pragma unroll
          for (int r = 0; r < 4; ++r) {
            const int m = m0 + wm * 64 + mt * 32 + g * 8 + e * 4 + r;
            const int bidx = m >> 11;
            const int s = m & 2047;
            const float val = acc[mt][nt][g * 4 + r] + bv;
            const unsigned short hv = f2bf(val);
            const size_t off =
                (size_t)(bidx * 16 + h) * (2048 * 64) + (size_t)s * 64 + d;
            k_h[off] = hv;
            k_l[off] = f2bf(val - bf2f(hv));
          }
      }
    }
  }
}

// ---------------------------------------------------------------------------
// Out-proj GEMM: A = vals single bf16, B = Wout hi/lo (2 MFMAs/product).
// 128x64 tile, 512 blocks. Writes fp32+bias directly to out.
// ---------------------------------------------------------------------------
__global__ __launch_bounds__(256) void gemm_out2(
    const unsigned short* __restrict__ A,
    const unsigned short* __restrict__ Bh, const unsigned short* __restrict__ Bl,
    const float* __restrict__ bias, float* __restrict__ out) {
  __shared__ unsigned short sm[8192];
  const int tid = threadIdx.x;
  const int lane = tid & 63;
  const int w = tid >> 6;
  const int wm = w >> 1;
  const int wn = w & 1;
  const int l31 = lane & 31;
  const int e = lane >> 5;
  const int m0 = blockIdx.x * 128;
  const int n0 = blockIdx.y * 64;

  int acoff[2], aldsb[2];
#pragma unroll
  for (int u = 0; u < 2; ++u) {
    const int slot = w * 128 + u * 64 + lane;
    acoff[u] = slot_src_off(slot, 1024);
    aldsb[u] = (w * 128 + u * 64) * 8;
  }
  const int bslot = w * 64 + lane;
  const int bcoff = slot_src_off(bslot, 1024);
  const int bldsb = bslot * 8;

  const unsigned short* Ap  = A + (size_t)m0 * 1024;
  const unsigned short* Bph = Bh + (size_t)n0 * 1024;
  const unsigned short* Bpl = Bl + (size_t)n0 * 1024;

  ffrag16 acc[2];
  acc[0] = (ffrag16)0.f;
  acc[1] = (ffrag16)0.f;

  int ca[2][2], cb[2];
#pragma unroll
  for (int t = 0; t < 2; ++t)
#pragma unroll
    for (int h2 = 0; h2 < 2; ++h2)
      ca[t][h2] = gemm_slot(wm * 64 + t * 32 + l31, h2 * 2 + e) * 8;
#pragma unroll
  for (int h2 = 0; h2 < 2; ++h2)
    cb[h2] = gemm_slot(wn * 32 + l31, h2 * 2 + e) * 8;

  for (int k0 = 0; k0 < 1024; k0 += 32) {
    __syncthreads();
#pragma unroll
    for (int u = 0; u < 2; ++u)
      async_copy16(&sm[0 + aldsb[u]], Ap + acoff[u] + k0);
    async_copy16(&sm[4096 + bldsb], Bph + bcoff + k0);
    async_copy16(&sm[6144 + bldsb], Bpl + bcoff + k0);
    __syncthreads();

    bfrag ah[2][2], bhf[2], blf[2];
#pragma unroll
    for (int t = 0; t < 2; ++t)
#pragma unroll
      for (int h2 = 0; h2 < 2; ++h2)
        ah[t][h2] = *(const bfrag*)&sm[0 + ca[t][h2]];
#pragma unroll
    for (int h2 = 0; h2 < 2; ++h2) {
      bhf[h2] = *(const bfrag*)&sm[4096 + cb[h2]];
      blf[h2] = *(const bfrag*)&sm[6144 + cb[h2]];
    }
#pragma unroll
    for (int mt = 0; mt < 2; ++mt)
#pragma unroll
      for (int h2 = 0; h2 < 2; ++h2) {
        acc[mt] = __builtin_amdgcn_mfma_f32_32x32x16_bf16(
            ah[mt][h2], bhf[h2], acc[mt], 0, 0, 0);
        acc[mt] = __builtin_amdgcn_mfma_f32_32x32x16_bf16(
            ah[mt][h2], blf[h2], acc[mt], 0, 0, 0);
      }
  }

  const int n = n0 + wn * 32 + l31;
  const float bv = bias[n];
#pragma unroll
  for (int mt = 0; mt < 2; ++mt)
#pragma unroll
    for (int g = 0; g < 4; ++g)
#pragma unroll
      for (int r = 0; r < 4; ++r) {
        const int m = m0 + wm * 64 + mt * 32 + g * 8 + e * 4 + r;
        out[(size_t)m * 1024 + n] = acc[mt][g * 4 + r] + bv;
      }
}

// ---------------------------------------------------------------------------
// Split-K balanced MFMA flash attention. Fixed-max softmax => O,l are plain
// sums => key-split is associative. Block (bh, y, z): pair-y rows, kt range
// z0:[y,E0) z1:[E0,32), E0 = y<=7 ? y+17 : 24 -> exactly 17/16 MFMA-units.
// Single-buffered staging (24KB) + P (16KB) = 40KB -> 4 blocks/CU; the 4-way
// block concurrency replaces the double-buffer's intra-block prefetch (m114).
// Writes RAW O partials (bf16) + l partials (fp32); merge_vals divides.
// Row-2047: fix wave (y==0,w==3, both z) writes partial Vsum + key count.
// ---------------------------------------------------------------------------
__global__ __launch_bounds__(256, 4) void attn_ks(
    const unsigned short* __restrict__ qh,
    const unsigned short* __restrict__ kh, const unsigned short* __restrict__ kl,
    const unsigned short* __restrict__ vth,
    unsigned short* __restrict__ pO, float* __restrict__ pl) {
  __shared__ unsigned short sm[12288 + 8192];  // Kh|Kl|Vh + P
  const int tid = threadIdx.x;
  const int lane = tid & 63;
  const int w = tid >> 6;
  const int l15 = lane & 15;
  const int quad = lane >> 4;
  const int bh = blockIdx.x;
  const int y = blockIdx.y;
  const int z = blockIdx.z;
  const int rbase[2] = {64 * y + 16 * w, 64 * (31 - y) + 16 * w};
  const int ktB = 31 - y;
  const int E0 = (y <= 7) ? (y + 17) : 24;
  const int kts = z ? E0 : y;
  const int kte = z ? 32 : E0;
  const bool fix = (y == 0) && (w == 3);  // owns row 2047
  const size_t base = (size_t)bh * (Ss * HDd);
  const int PB = 12288;  // P region base (shorts)

  bfrag Qh[2][2];
#pragma unroll
  for (int mt = 0; mt < 2; ++mt)
#pragma unroll
    for (int ks = 0; ks < 2; ++ks) {
      const size_t off = base + (size_t)(rbase[mt] + l15) * 64 + ks * 32 + quad * 8;
      Qh[mt][ks] = *(const bfrag*)(qh + off);
    }

  bfrag vone;
#pragma unroll
  for (int j = 0; j < 8; ++j) vone[j] = (short)0x3F80;  // bf16 1.0

  const int c0 = w * 128 + lane;
  const int c1 = c0 + 64;
  const int r0 = c0 >> 3, r1 = c1 >> 3;
  const int s0 = ((c0 & 7) ^ (r0 & 7)) * 8;
  const int s1 = ((c1 & 7) ^ (r1 & 7)) * 8;
  const int koff0 = r0 * 64 + s0, koff1 = r1 * 64 + s1;
  const int voff0 = r0 * 2048 + s0, voff1 = r1 * 2048 + s1;
  const int ldsc0 = (w * 128) * 8;
  const int ldsc1 = (w * 128 + 64) * 8;

  ffrag O[2][4], Oe[2], Vsum[4];
#pragma unroll
  for (int mt = 0; mt < 2; ++mt) {
#pragma unroll
    for (int dt = 0; dt < 4; ++dt) O[mt][dt] = (ffrag)0.f;
    Oe[mt] = (ffrag)0.f;
  }
#pragma unroll
  for (int dt = 0; dt < 4; ++dt) Vsum[dt] = (ffrag)0.f;

  for (int kt = kts; kt < kte; ++kt) {
    const unsigned short* kph = kh + base + kt * 4096;
    const unsigned short* kpl = kl + base + kt * 4096;
    const unsigned short* vph = vth + base + kt * 64;
    __syncthreads();  // prior iter's LDS reads done
    async_copy16(&sm[0 + ldsc0], kph + koff0);
    async_copy16(&sm[0 + ldsc1], kph + koff1);
    async_copy16(&sm[4096 + ldsc0], kpl + koff0);
    async_copy16(&sm[4096 + ldsc1], kpl + koff1);
    async_copy16(&sm[8192 + ldsc0], vph + voff0);
    async_copy16(&sm[8192 + ldsc1], vph + voff1);
    __syncthreads();  // vmcnt drained before release

    const bool bact = (kt >= ktB);

    // ---- S = Q K^T (Q pre-scaled; K = Kh + Kl)
    ffrag S[2][4];
#pragma unroll
    for (int mt = 0; mt < 2; ++mt)
#pragma unroll
      for (int nt = 0; nt < 4; ++nt) S[mt][nt] = (ffrag)0.f;
#pragma unroll
    for (int nt = 0; nt < 4; ++nt) {
      const int krow = nt * 16 + l15;
#pragma unroll
      for (int ks = 0; ks < 2; ++ks) {
        const int koffr = krow * 64 + ((ks * 4 + quad) ^ (krow & 7)) * 8;
        const bfrag kbh = *(const bfrag*)&sm[koffr];
        const bfrag kbl = *(const bfrag*)&sm[4096 + koffr];
        S[0][nt] = __builtin_amdgcn_mfma_f32_16x16x32_bf16(Qh[0][ks], kbh, S[0][nt], 0, 0, 0);
        S[0][nt] = __builtin_amdgcn_mfma_f32_16x16x32_bf16(Qh[0][ks], kbl, S[0][nt], 0, 0, 0);
        if (bact) {
          S[1][nt] = __builtin_amdgcn_mfma_f32_16x16x32_bf16(Qh[1][ks], kbh, S[1][nt], 0, 0, 0);
          S[1][nt] = __builtin_amdgcn_mfma_f32_16x16x32_bf16(Qh[1][ks], kbl, S[1][nt], 0, 0, 0);
        }
      }
    }

    // ---- p = exp2(S [+ CM if masked]); packed bf16 cvt; store to P LDS
    const float CM = -1.442695041e9f;  // -1e9 * log2(e)
#pragma unroll
    for (int mt = 0; mt < 2; ++mt) {
      if (mt == 1 && !bact) continue;
      const bool partial = (kt == (mt == 0 ? y : ktB));
#pragma unroll
      for (int nt = 0; nt < 4; ++nt) {
        const int key = nt * 16 + l15;
#pragma unroll
        for (int rp = 0; rp < 2; ++rp) {
          float t0 = S[mt][nt][2 * rp];
          float t1 = S[mt][nt][2 * rp + 1];
          if (partial) {
            const int jg = kt * 64 + key;
            const int ig = rbase[mt] + quad * 4 + 2 * rp;
            if (jg <= ig) t0 += CM;
            if (jg <= ig + 1) t1 += CM;
          }
          float2 pf;
          pf.x = __builtin_amdgcn_exp2f(t0);
          pf.y = __builtin_amdgcn_exp2f(t1);
          const __hip_bfloat162 pb = __float22bfloat162_rn(pf);
          const unsigned short* pbs = (const unsigned short*)&pb;
          const int prow0 = w * 32 + mt * 16 + quad * 4 + 2 * rp;
          sm[PB + prow0 * 64 + (((key >> 3) ^ (prow0 & 7)) * 8 + (key & 7))] = pbs[0];
          const int prow1 = prow0 + 1;
          sm[PB + prow1 * 64 + (((key >> 3) ^ (prow1 & 7)) * 8 + (key & 7))] = pbs[1];
        }
      }
    }

    // ---- PV (V single) + l via ones-MFMA (+ Vsum on the fix wave)
#pragma unroll
    for (int ks = 0; ks < 2; ++ks) {
      bfrag pA[2];
#pragma unroll
      for (int mt = 0; mt < 2; ++mt) {
        if (mt == 1 && !bact) continue;
        const int prow = w * 32 + mt * 16 + l15;
        pA[mt] = *(const bfrag*)&sm[PB + prow * 64 + ((ks * 4 + quad) ^ (prow & 7)) * 8];
      }
      Oe[0] = __builtin_amdgcn_mfma_f32_16x16x32_bf16(pA[0], vone, Oe[0], 0, 0, 0);
      if (bact)
        Oe[1] = __builtin_amdgcn_mfma_f32_16x16x32_bf16(pA[1], vone, Oe[1], 0, 0, 0);
#pragma unroll
      for (int dt = 0; dt < 4; ++dt) {
        const int vrow = dt * 16 + l15;
        const int voffr = 8192 + vrow * 64 + ((ks * 4 + quad) ^ (vrow & 7)) * 8;
        const bfrag vbh = *(const bfrag*)&sm[voffr];
        O[0][dt] = __builtin_amdgcn_mfma_f32_16x16x32_bf16(pA[0], vbh, O[0][dt], 0, 0, 0);
        if (bact)
          O[1][dt] = __builtin_amdgcn_mfma_f32_16x16x32_bf16(pA[1], vbh, O[1][dt], 0, 0, 0);
        if (fix)
          Vsum[dt] = __builtin_amdgcn_mfma_f32_16x16x32_bf16(vone, vbh, Vsum[dt], 0, 0, 0);
      }
    }
  }

  // ---- epilogue: RAW partials. pO[z][bh][s][d] bf16, pl[z][bh*2048+s] f32.
  // Row 2047: normal path gives exactly 0 (all p masked to 0) -> substitute
  // partial Vsum and key count; merge then yields mean(V).
  const size_t pbase = (size_t)z * (32 * 2048 * 64) + (size_t)bh * (2048 * 64);
  const int lbase = z * 65536 + bh * 2048;
  const float lfix = 64.0f * (float)(kte - kts);
#pragma unroll
  for (int mt = 0; mt < 2; ++mt)
#pragma unroll
    for (int r = 0; r < 4; ++r) {
      const int s = rbase[mt] + quad * 4 + r;
      const bool fl = fix && mt == 1 && quad == 3 && r == 3;  // s == 2047
#pragma unroll
      for (int dt = 0; dt < 4; ++dt) {
        const float val = fl ? Vsum[dt][r] : O[mt][dt][r];
        pO[pbase + (size_t)s * 64 + dt * 16 + l15] = f2bf(val);
      }
      if (l15 == 0) pl[lbase + s] = fl ? lfix : Oe[mt][r];
    }
}

// ---------------------------------------------------------------------------
// Merge: vals[b][s][h*64+d] = bf16( (O0+O1) / (l0+l1) ). 4M elems.
// ---------------------------------------------------------------------------
__global__ __launch_bounds__(256) void merge_vals(
    const unsigned short* __restrict__ pO, const float* __restrict__ pl,
    unsigned short* __restrict__ vals) {
  const int idx = (blockIdx.x * 256 + threadIdx.x) * 4;
  const int d = idx & 63;
  const int sbh = idx >> 6;       // bh*2048 + s
  const int s = sbh & 2047;
  const int bh = sbh >> 11;
  const size_t zstr = (size_t)32 * 2048 * 64;
  const ushort4 o0 = *(const ushort4*)(pO + (size_t)sbh * 64 + d);
  const ushort4 o1 = *(const ushort4*)(pO + zstr + (size_t)sbh * 64 + d);
  const float inv = 1.0f / (pl[sbh] + pl[65536 + sbh]);
  ushort4 rv;
  rv.x = f2bf((bf2f(o0.x) + bf2f(o1.x)) * inv);
  rv.y = f2bf((bf2f(o0.y) + bf2f(o1.y)) * inv);
  rv.z = f2bf((bf2f(o0.z) + bf2f(o1.z)) * inv);
  rv.w = f2bf((bf2f(o0.w) + bf2f(o1.w)) * inv);
  const int b = bh >> 4;
  const int h = bh & 15;
  *(ushort4*)(vals + ((size_t)b * 2048 + s) * 1024 + h * 64 + d) = rv;
}

// ---------------------------------------------------------------------------
// ws (64 MB): qh[0,8) kh[8,16) kl[16,24) vth[24,32) vals[32,40)
// pO[40,56) pl[56,56.5)   (pO/pl overlay dead wq region [48,60))
// wqh[48,54) wql[54,60) woh[60,62) wol[62,64)  (wq dead after gemm_qkv).
// d_out: xh[0,8) (dead after gemm_qkv); gemm_out2 writes final fp32 directly.
// ---------------------------------------------------------------------------
extern "C" void kernel_launch(void* const* d_in, const int* in_sizes, int n_in,
                              void* d_out, int out_size, void* d_ws, size_t ws_size,
                              hipStream_t stream) {
  const float* x    = (const float*)d_in[0];
  const float* Wqkv = (const float*)d_in[1];
  const float* bqkv = (const float*)d_in[2];
  const float* Wout = (const float*)d_in[3];
  const float* bout = (const float*)d_in[4];
  float* out = (float*)d_out;
  char* wsb = (char*)d_ws;

  unsigned short* qhp  = (unsigned short*)d_ws;
  unsigned short* khp  = qhp + 1 * 4194304;
  unsigned short* klp  = qhp + 2 * 4194304;
  unsigned short* vthp = qhp + 3 * 4194304;
  unsigned short* vals = qhp + 4 * 4194304;
  unsigned short* pO   = (unsigned short*)(wsb + (40u << 20));  // 16 MB
  float*          pl   = (float*)(wsb + (56u << 20));           // 512 KB
  unsigned short* wqh  = (unsigned short*)(wsb + (48u << 20));
  unsigned short* wql  = (unsigned short*)(wsb + (54u << 20));
  unsigned short* woh  = (unsigned short*)(wsb + (60u << 20));
  unsigned short* wol  = (unsigned short*)(wsb + (62u << 20));
  unsigned short* xh   = (unsigned short*)d_out;

  dim3 blk(256);
  split_all<<<8192, blk, 0, stream>>>(x, xh, Wqkv, wqh, wql, Wout, woh, wol);
  gemm_qkv<<<dim3(32, 24), blk, 0, stream>>>(xh, wqh, wql, bqkv,
                                             qhp, khp, klp, vthp);
  attn_ks<<<dim3(32, 16, 2), blk, 0, stream>>>(qhp, khp, klp, vthp, pO, pl);
  merge_vals<<<4096, blk, 0, stream>>>(pO, pl, vals);
  gemm_out2<<<dim3(32, 16), blk, 0, stream>>>(vals, woh, wol, bout, out);
}

// Round 12
// 232.279 us; speedup vs baseline: 1.4226x; 1.4226x over previous
//
#include <hip/hip_runtime.h>
#include <hip/hip_bf16.h>
#include <math.h>

#define Bb 2
#define Ss 2048
#define Ee 1024
#define Hh 16
#define HDd 64
#define NEG_INF_F -1000000000.0f

typedef __attribute__((ext_vector_type(8))) short bfrag;     // 8 bf16
typedef __attribute__((ext_vector_type(4))) float ffrag;     // 16x16 C/D
typedef __attribute__((ext_vector_type(16))) float ffrag16;  // 32x32 C/D
typedef __attribute__((ext_vector_type(8))) unsigned short us8;

#define C1F 0.1803368801f  /* 0.125 * log2(e) — folded into Q at gemm_qkv */

// ---- bf16 helpers ----------------------------------------------------------
__device__ __forceinline__ unsigned short f2bf(float x) {
  unsigned u = __float_as_uint(x);
  u += 0x7fffu + ((u >> 16) & 1u);
  return (unsigned short)(u >> 16);
}
__device__ __forceinline__ float bf2f(unsigned short h) {
  return __uint_as_float(((unsigned)h) << 16);
}

__device__ __forceinline__ void async_copy16(void* lds, const void* g) {
  __builtin_amdgcn_global_load_lds(
      (const __attribute__((address_space(1))) unsigned int*)g,
      (__attribute__((address_space(3))) unsigned int*)lds, 16, 0, 0);
}

// ---------------------------------------------------------------------------
// Fused split pass: x (4M) -> hi only; Wqkv (3M), Wout (1M) -> hi/lo.
// ---------------------------------------------------------------------------
__global__ __launch_bounds__(256) void split_all(
    const float* __restrict__ x, unsigned short* __restrict__ xh,
    const float* __restrict__ wq, unsigned short* __restrict__ wqh,
    unsigned short* __restrict__ wql,
    const float* __restrict__ wo, unsigned short* __restrict__ woh,
    unsigned short* __restrict__ wol) {
  int bid = blockIdx.x;
  const float* in;
  unsigned short *hi, *lo;
  if (bid < 4096) { in = x; hi = xh; lo = nullptr; }
  else if (bid < 7168) { bid -= 4096; in = wq; hi = wqh; lo = wql; }
  else { bid -= 7168; in = wo; hi = woh; lo = wol; }
  const int idx = (bid * 256 + threadIdx.x) * 4;
  const float4 v = *(const float4*)(in + idx);
  unsigned short h0 = f2bf(v.x), h1 = f2bf(v.y), h2 = f2bf(v.z), h3 = f2bf(v.w);
  ushort4 hv = {h0, h1, h2, h3};
  *(ushort4*)(hi + idx) = hv;
  if (lo) {
    ushort4 lv = {f2bf(v.x - bf2f(h0)), f2bf(v.y - bf2f(h1)),
                  f2bf(v.z - bf2f(h2)), f2bf(v.w - bf2f(h3))};
    *(ushort4*)(lo + idx) = lv;
  }
}

// ---------------------------------------------------------------------------
// LDS slot map (rows of 32 bf16 = 4 x 16B chunks):
// slot(row,q) = (row>>1)*8 + ((((row&1)*4)|q) ^ ((row>>1)&7)).
// ---------------------------------------------------------------------------
__device__ __forceinline__ int gemm_slot(int row, int q) {
  return (row >> 1) * 8 + ((((row & 1) * 4) | q) ^ ((row >> 1) & 7));
}
__device__ __forceinline__ int slot_src_off(int slot, int ld) {
  const int dr = slot >> 3;
  const int idx8 = (slot & 7) ^ (dr & 7);
  const int row = dr * 2 + (idx8 >> 2);
  const int q = idx8 & 3;
  return row * ld + q * 8;
}

// ---------------------------------------------------------------------------
// QKV GEMM, 32x32x16 core: C = xh * (Wh + Wl)^T + bias (2 MFMAs/product).
// 128x128 tile. Epilogue: Q single bf16 pre-scaled by C1F -> [bh][s][64];
// K hi/lo -> [bh][s][64]; V single bf16 transposed -> [bh][d][s].
// ---------------------------------------------------------------------------
__global__ __launch_bounds__(256) void gemm_qkv(
    const unsigned short* __restrict__ Ah,
    const unsigned short* __restrict__ Bh, const unsigned short* __restrict__ Bl,
    const float* __restrict__ bias,
    unsigned short* __restrict__ q_h,
    unsigned short* __restrict__ k_h, unsigned short* __restrict__ k_l,
    unsigned short* __restrict__ vt_h) {
  __shared__ unsigned short sm[3 * 4096];
  const int tid = threadIdx.x;
  const int lane = tid & 63;
  const int w = tid >> 6;
  const int wm = w >> 1;
  const int wn = w & 1;
  const int l31 = lane & 31;
  const int e = lane >> 5;
  const int m0 = blockIdx.x * 128;
  const int n0 = blockIdx.y * 128;

  int coff[2], ldsb[2];
#pragma unroll
  for (int u = 0; u < 2; ++u) {
    const int slot = w * 128 + u * 64 + lane;
    coff[u] = slot_src_off(slot, 1024);
    ldsb[u] = (w * 128 + u * 64) * 8;
  }
  const unsigned short* srcs[3] = {
      Ah + (size_t)m0 * 1024, Bh + (size_t)n0 * 1024, Bl + (size_t)n0 * 1024};

  ffrag16 acc[2][2];
#pragma unroll
  for (int i = 0; i < 2; ++i)
#pragma unroll
    for (int j = 0; j < 2; ++j) acc[i][j] = (ffrag16)0.f;

  int ca[2][2], cb[2][2];
#pragma unroll
  for (int t = 0; t < 2; ++t)
#pragma unroll
    for (int h2 = 0; h2 < 2; ++h2) {
      ca[t][h2] = gemm_slot(wm * 64 + t * 32 + l31, h2 * 2 + e) * 8;
      cb[t][h2] = gemm_slot(wn * 64 + t * 32 + l31, h2 * 2 + e) * 8;
    }

  for (int k0 = 0; k0 < 1024; k0 += 32) {
    __syncthreads();
#pragma unroll
    for (int t = 0; t < 3; ++t)
#pragma unroll
      for (int u = 0; u < 2; ++u)
        async_copy16(&sm[t * 4096 + ldsb[u]], srcs[t] + coff[u] + k0);
    __syncthreads();

    bfrag ah[2][2], bhf[2][2], blf[2][2];
#pragma unroll
    for (int t = 0; t < 2; ++t)
#pragma unroll
      for (int h2 = 0; h2 < 2; ++h2) {
        ah[t][h2] = *(const bfrag*)&sm[0 * 4096 + ca[t][h2]];
        bhf[t][h2] = *(const bfrag*)&sm[1 * 4096 + cb[t][h2]];
        blf[t][h2] = *(const bfrag*)&sm[2 * 4096 + cb[t][h2]];
      }
#pragma unroll
    for (int mt = 0; mt < 2; ++mt)
#pragma unroll
      for (int nt = 0; nt < 2; ++nt)
#pragma unroll
        for (int h2 = 0; h2 < 2; ++h2) {
          acc[mt][nt] = __builtin_amdgcn_mfma_f32_32x32x16_bf16(
              ah[mt][h2], bhf[nt][h2], acc[mt][nt], 0, 0, 0);
          acc[mt][nt] = __builtin_amdgcn_mfma_f32_32x32x16_bf16(
              ah[mt][h2], blf[nt][h2], acc[mt][nt], 0, 0, 0);
        }
  }

#pragma unroll
  for (int nt = 0; nt < 2; ++nt) {
    const int n = n0 + wn * 64 + nt * 32 + l31;
    const float bv = bias[n];
    const int h = n / 192;
    const int c = n - h * 192;
    const int d = c & 63;
#pragma unroll
    for (int mt = 0; mt < 2; ++mt) {
      if (c >= 128) {
#pragma unroll
        for (int g = 0; g < 4; ++g) {
          const int m = m0 + wm * 64 + mt * 32 + g * 8 + e * 4;
          const int bidx = m >> 11;
          const int s = m & 2047;
          ushort4 hv4;
          unsigned short* ph = (unsigned short*)&hv4;
#pragma unroll
          for (int r = 0; r < 4; ++r)
            ph[r] = f2bf(acc[mt][nt][g * 4 + r] + bv);
          const size_t off =
              (size_t)(bidx * 16 + h) * (64 * 2048) + (size_t)d * 2048 + s;
          *(ushort4*)(vt_h + off) = hv4;
        }
      } else if (c < 64) {
#pragma unroll
        for (int g = 0; g < 4; ++g)
#pragma unroll
          for (int r = 0; r < 4; ++r) {
            const int m = m0 + wm * 64 + mt * 32 + g * 8 + e * 4 + r;
            const int bidx = m >> 11;
            const int s = m & 2047;
            const size_t off =
                (size_t)(bidx * 16 + h) * (2048 * 64) + (size_t)s * 64 + d;
            q_h[off] = f2bf((acc[mt][nt][g * 4 + r] + bv) * C1F);
          }
      } else {
#pragma unroll
        for (int g = 0; g < 4; ++g)
#pragma unroll
          for (int r = 0; r < 4; ++r) {
            const int m = m0 + wm * 64 + mt * 32 + g * 8 + e * 4 + r;
            const int bidx = m >> 11;
            const int s = m & 2047;
            const float val = acc[mt][nt][g * 4 + r] + bv;
            const unsigned short hv = f2bf(val);
            const size_t off =
                (size_t)(bidx * 16 + h) * (2048 * 64) + (size_t)s * 64 + d;
            k_h[off] = hv;
            k_l[off] = f2bf(val - bf2f(hv));
          }
      }
    }
  }
}

// ---------------------------------------------------------------------------
// Out-proj GEMM: A = vals single bf16, B = Wout hi/lo (2 MFMAs/product).
// 128x64 tile, 512 blocks. Writes fp32+bias directly to out.
// ---------------------------------------------------------------------------
__global__ __launch_bounds__(256) void gemm_out2(
    const unsigned short* __restrict__ A,
    const unsigned short* __restrict__ Bh, const unsigned short* __restrict__ Bl,
    const float* __restrict__ bias, float* __restrict__ out) {
  __shared__ unsigned short sm[8192];
  const int tid = threadIdx.x;
  const int lane = tid & 63;
  const int w = tid >> 6;
  const int wm = w >> 1;
  const int wn = w & 1;
  const int l31 = lane & 31;
  const int e = lane >> 5;
  const int m0 = blockIdx.x * 128;
  const int n0 = blockIdx.y * 64;

  int acoff[2], aldsb[2];
#pragma unroll
  for (int u = 0; u < 2; ++u) {
    const int slot = w * 128 + u * 64 + lane;
    acoff[u] = slot_src_off(slot, 1024);
    aldsb[u] = (w * 128 + u * 64) * 8;
  }
  const int bslot = w * 64 + lane;
  const int bcoff = slot_src_off(bslot, 1024);
  const int bldsb = bslot * 8;

  const unsigned short* Ap  = A + (size_t)m0 * 1024;
  const unsigned short* Bph = Bh + (size_t)n0 * 1024;
  const unsigned short* Bpl = Bl + (size_t)n0 * 1024;

  ffrag16 acc[2];
  acc[0] = (ffrag16)0.f;
  acc[1] = (ffrag16)0.f;

  int ca[2][2], cb[2];
#pragma unroll
  for (int t = 0; t < 2; ++t)
#pragma unroll
    for (int h2 = 0; h2 < 2; ++h2)
      ca[t][h2] = gemm_slot(wm * 64 + t * 32 + l31, h2 * 2 + e) * 8;
#pragma unroll
  for (int h2 = 0; h2 < 2; ++h2)
    cb[h2] = gemm_slot(wn * 32 + l31, h2 * 2 + e) * 8;

  for (int k0 = 0; k0 < 1024; k0 += 32) {
    __syncthreads();
#pragma unroll
    for (int u = 0; u < 2; ++u)
      async_copy16(&sm[0 + aldsb[u]], Ap + acoff[u] + k0);
    async_copy16(&sm[4096 + bldsb], Bph + bcoff + k0);
    async_copy16(&sm[6144 + bldsb], Bpl + bcoff + k0);
    __syncthreads();

    bfrag ah[2][2], bhf[2], blf[2];
#pragma unroll
    for (int t = 0; t < 2; ++t)
#pragma unroll
      for (int h2 = 0; h2 < 2; ++h2)
        ah[t][h2] = *(const bfrag*)&sm[0 + ca[t][h2]];
#pragma unroll
    for (int h2 = 0; h2 < 2; ++h2) {
      bhf[h2] = *(const bfrag*)&sm[4096 + cb[h2]];
      blf[h2] = *(const bfrag*)&sm[6144 + cb[h2]];
    }
#pragma unroll
    for (int mt = 0; mt < 2; ++mt)
#pragma unroll
      for (int h2 = 0; h2 < 2; ++h2) {
        acc[mt] = __builtin_amdgcn_mfma_f32_32x32x16_bf16(
            ah[mt][h2], bhf[h2], acc[mt], 0, 0, 0);
        acc[mt] = __builtin_amdgcn_mfma_f32_32x32x16_bf16(
            ah[mt][h2], blf[h2], acc[mt], 0, 0, 0);
      }
  }

  const int n = n0 + wn * 32 + l31;
  const float bv = bias[n];
#pragma unroll
  for (int mt = 0; mt < 2; ++mt)
#pragma unroll
    for (int g = 0; g < 4; ++g)
#pragma unroll
      for (int r = 0; r < 4; ++r) {
        const int m = m0 + wm * 64 + mt * 32 + g * 8 + e * 4 + r;
        out[(size_t)m * 1024 + n] = acc[mt][g * 4 + r] + bv;
      }
}

// ---------------------------------------------------------------------------
// Split-K balanced MFMA flash attention. Fixed-max softmax => O,l are plain
// sums => key-split is associative. Block (bh, y, z): pair-y rows, kt range
// z0:[y,E0) z1:[E0,32), E0 = y<=7 ? y+17 : 24 -> exactly 17/16 MFMA-units.
// Single-buffered staging (24KB) + P (16KB) = 40KB.
// NOTE: plain __launch_bounds__(256) — R11's (256,4) forced VGPR=64 and the
// accumulators spilled to scratch (FETCH 319MB, 2.4x regression). Natural
// allocation ~116 VGPR <= 128 gives the intended 4 blocks/CU without spills.
// Writes RAW O partials (bf16) + l partials (fp32); merge_vals divides.
// Row-2047: fix wave (y==0,w==3, both z) writes partial Vsum + key count.
// ---------------------------------------------------------------------------
__global__ __launch_bounds__(256) void attn_ks(
    const unsigned short* __restrict__ qh,
    const unsigned short* __restrict__ kh, const unsigned short* __restrict__ kl,
    const unsigned short* __restrict__ vth,
    unsigned short* __restrict__ pO, float* __restrict__ pl) {
  __shared__ unsigned short sm[12288 + 8192];  // Kh|Kl|Vh + P
  const int tid = threadIdx.x;
  const int lane = tid & 63;
  const int w = tid >> 6;
  const int l15 = lane & 15;
  const int quad = lane >> 4;
  const int bh = blockIdx.x;
  const int y = blockIdx.y;
  const int z = blockIdx.z;
  const int rbase[2] = {64 * y + 16 * w, 64 * (31 - y) + 16 * w};
  const int ktB = 31 - y;
  const int E0 = (y <= 7) ? (y + 17) : 24;
  const int kts = z ? E0 : y;
  const int kte = z ? 32 : E0;
  const bool fix = (y == 0) && (w == 3);  // owns row 2047
  const size_t base = (size_t)bh * (Ss * HDd);
  const int PB = 12288;  // P region base (shorts)

  bfrag Qh[2][2];
#pragma unroll
  for (int mt = 0; mt < 2; ++mt)
#pragma unroll
    for (int ks = 0; ks < 2; ++ks) {
      const size_t off = base + (size_t)(rbase[mt] + l15) * 64 + ks * 32 + quad * 8;
      Qh[mt][ks] = *(const bfrag*)(qh + off);
    }

  bfrag vone;
#pragma unroll
  for (int j = 0; j < 8; ++j) vone[j] = (short)0x3F80;  // bf16 1.0

  const int c0 = w * 128 + lane;
  const int c1 = c0 + 64;
  const int r0 = c0 >> 3, r1 = c1 >> 3;
  const int s0 = ((c0 & 7) ^ (r0 & 7)) * 8;
  const int s1 = ((c1 & 7) ^ (r1 & 7)) * 8;
  const int koff0 = r0 * 64 + s0, koff1 = r1 * 64 + s1;
  const int voff0 = r0 * 2048 + s0, voff1 = r1 * 2048 + s1;
  const int ldsc0 = (w * 128) * 8;
  const int ldsc1 = (w * 128 + 64) * 8;

  ffrag O[2][4], Oe[2], Vsum[4];
#pragma unroll
  for (int mt = 0; mt < 2; ++mt) {
#pragma unroll
    for (int dt = 0; dt < 4; ++dt) O[mt][dt] = (ffrag)0.f;
    Oe[mt] = (ffrag)0.f;
  }
#pragma unroll
  for (int dt = 0; dt < 4; ++dt) Vsum[dt] = (ffrag)0.f;

  for (int kt = kts; kt < kte; ++kt) {
    const unsigned short* kph = kh + base + kt * 4096;
    const unsigned short* kpl = kl + base + kt * 4096;
    const unsigned short* vph = vth + base + kt * 64;
    __syncthreads();  // prior iter's LDS reads done
    async_copy16(&sm[0 + ldsc0], kph + koff0);
    async_copy16(&sm[0 + ldsc1], kph + koff1);
    async_copy16(&sm[4096 + ldsc0], kpl + koff0);
    async_copy16(&sm[4096 + ldsc1], kpl + koff1);
    async_copy16(&sm[8192 + ldsc0], vph + voff0);
    async_copy16(&sm[8192 + ldsc1], vph + voff1);
    __syncthreads();  // vmcnt drained before release

    const bool bact = (kt >= ktB);

    // ---- S = Q K^T (Q pre-scaled; K = Kh + Kl)
    ffrag S[2][4];
#pragma unroll
    for (int mt = 0; mt < 2; ++mt)
#pragma unroll
      for (int nt = 0; nt < 4; ++nt) S[mt][nt] = (ffrag)0.f;
#pragma unroll
    for (int nt = 0; nt < 4; ++nt) {
      const int krow = nt * 16 + l15;
#pragma unroll
      for (int ks = 0; ks < 2; ++ks) {
        const int koffr = krow * 64 + ((ks * 4 + quad) ^ (krow & 7)) * 8;
        const bfrag kbh = *(const bfrag*)&sm[koffr];
        const bfrag kbl = *(const bfrag*)&sm[4096 + koffr];
        S[0][nt] = __builtin_amdgcn_mfma_f32_16x16x32_bf16(Qh[0][ks], kbh, S[0][nt], 0, 0, 0);
        S[0][nt] = __builtin_amdgcn_mfma_f32_16x16x32_bf16(Qh[0][ks], kbl, S[0][nt], 0, 0, 0);
        if (bact) {
          S[1][nt] = __builtin_amdgcn_mfma_f32_16x16x32_bf16(Qh[1][ks], kbh, S[1][nt], 0, 0, 0);
          S[1][nt] = __builtin_amdgcn_mfma_f32_16x16x32_bf16(Qh[1][ks], kbl, S[1][nt], 0, 0, 0);
        }
      }
    }

    // ---- p = exp2(S [+ CM if masked]); packed bf16 cvt; store to P LDS
    const float CM = -1.442695041e9f;  // -1e9 * log2(e)
#pragma unroll
    for (int mt = 0; mt < 2; ++mt) {
      if (mt == 1 && !bact) continue;
      const bool partial = (kt == (mt == 0 ? y : ktB));
#pragma unroll
      for (int nt = 0; nt < 4; ++nt) {
        const int key = nt * 16 + l15;
#pragma unroll
        for (int rp = 0; rp < 2; ++rp) {
          float t0 = S[mt][nt][2 * rp];
          float t1 = S[mt][nt][2 * rp + 1];
          if (partial) {
            const int jg = kt * 64 + key;
            const int ig = rbase[mt] + quad * 4 + 2 * rp;
            if (jg <= ig) t0 += CM;
            if (jg <= ig + 1) t1 += CM;
          }
          float2 pf;
          pf.x = __builtin_amdgcn_exp2f(t0);
          pf.y = __builtin_amdgcn_exp2f(t1);
          const __hip_bfloat162 pb = __float22bfloat162_rn(pf);
          const unsigned short* pbs = (const unsigned short*)&pb;
          const int prow0 = w * 32 + mt * 16 + quad * 4 + 2 * rp;
          sm[PB + prow0 * 64 + (((key >> 3) ^ (prow0 & 7)) * 8 + (key & 7))] = pbs[0];
          const int prow1 = prow0 + 1;
          sm[PB + prow1 * 64 + (((key >> 3) ^ (prow1 & 7)) * 8 + (key & 7))] = pbs[1];
        }
      }
    }

    // ---- PV (V single) + l via ones-MFMA (+ Vsum on the fix wave)
#pragma unroll
    for (int ks = 0; ks < 2; ++ks) {
      bfrag pA[2];
#pragma unroll
      for (int mt = 0; mt < 2; ++mt) {
        if (mt == 1 && !bact) continue;
        const int prow = w * 32 + mt * 16 + l15;
        pA[mt] = *(const bfrag*)&sm[PB + prow * 64 + ((ks * 4 + quad) ^ (prow & 7)) * 8];
      }
      Oe[0] = __builtin_amdgcn_mfma_f32_16x16x32_bf16(pA[0], vone, Oe[0], 0, 0, 0);
      if (bact)
        Oe[1] = __builtin_amdgcn_mfma_f32_16x16x32_bf16(pA[1], vone, Oe[1], 0, 0, 0);
#pragma unroll
      for (int dt = 0; dt < 4; ++dt) {
        const int vrow = dt * 16 + l15;
        const int voffr = 8192 + vrow * 64 + ((ks * 4 + quad) ^ (vrow & 7)) * 8;
        const bfrag vbh = *(const bfrag*)&sm[voffr];
        O[0][dt] = __builtin_amdgcn_mfma_f32_16x16x32_bf16(pA[0], vbh, O[0][dt], 0, 0, 0);
        if (bact)
          O[1][dt] = __builtin_amdgcn_mfma_f32_16x16x32_bf16(pA[1], vbh, O[1][dt], 0, 0, 0);
        if (fix)
          Vsum[dt] = __builtin_amdgcn_mfma_f32_16x16x32_bf16(vone, vbh, Vsum[dt], 0, 0, 0);
      }
    }
  }

  // ---- epilogue: RAW partials. pO[z][bh][s][d] bf16, pl[z][bh*2048+s] f32.
  // Row 2047: normal path gives exactly 0 (all p masked to 0) -> substitute
  // partial Vsum and key count; merge then yields mean(V).
  const size_t pbase = (size_t)z * (32 * 2048 * 64) + (size_t)bh * (2048 * 64);
  const int lbase = z * 65536 + bh * 2048;
  const float lfix = 64.0f * (float)(kte - kts);
#pragma unroll
  for (int mt = 0; mt < 2; ++mt)
#pragma unroll
    for (int r = 0; r < 4; ++r) {
      const int s = rbase[mt] + quad * 4 + r;
      const bool fl = fix && mt == 1 && quad == 3 && r == 3;  // s == 2047
#pragma unroll
      for (int dt = 0; dt < 4; ++dt) {
        const float val = fl ? Vsum[dt][r] : O[mt][dt][r];
        pO[pbase + (size_t)s * 64 + dt * 16 + l15] = f2bf(val);
      }
      if (l15 == 0) pl[lbase + s] = fl ? lfix : Oe[mt][r];
    }
}

// ---------------------------------------------------------------------------
// Merge: vals[b][s][h*64+d] = bf16( (O0+O1) / (l0+l1) ). 4M elems.
// ---------------------------------------------------------------------------
__global__ __launch_bounds__(256) void merge_vals(
    const unsigned short* __restrict__ pO, const float* __restrict__ pl,
    unsigned short* __restrict__ vals) {
  const int idx = (blockIdx.x * 256 + threadIdx.x) * 4;
  const int d = idx & 63;
  const int sbh = idx >> 6;       // bh*2048 + s
  const int s = sbh & 2047;
  const int bh = sbh >> 11;
  const size_t zstr = (size_t)32 * 2048 * 64;
  const ushort4 o0 = *(const ushort4*)(pO + (size_t)sbh * 64 + d);
  const ushort4 o1 = *(const ushort4*)(pO + zstr + (size_t)sbh * 64 + d);
  const float inv = 1.0f / (pl[sbh] + pl[65536 + sbh]);
  ushort4 rv;
  rv.x = f2bf((bf2f(o0.x) + bf2f(o1.x)) * inv);
  rv.y = f2bf((bf2f(o0.y) + bf2f(o1.y)) * inv);
  rv.z = f2bf((bf2f(o0.z) + bf2f(o1.z)) * inv);
  rv.w = f2bf((bf2f(o0.w) + bf2f(o1.w)) * inv);
  const int b = bh >> 4;
  const int h = bh & 15;
  *(ushort4*)(vals + ((size_t)b * 2048 + s) * 1024 + h * 64 + d) = rv;
}

// ---------------------------------------------------------------------------
// ws (64 MB): qh[0,8) kh[8,16) kl[16,24) vth[24,32) vals[32,40)
// pO[40,56) pl[56,56.5)   (pO/pl overlay dead wq region [48,60))
// wqh[48,54) wql[54,60) woh[60,62) wol[62,64)  (wq dead after gemm_qkv).
// d_out: xh[0,8) (dead after gemm_qkv); gemm_out2 writes final fp32 directly.
// ---------------------------------------------------------------------------
extern "C" void kernel_launch(void* const* d_in, const int* in_sizes, int n_in,
                              void* d_out, int out_size, void* d_ws, size_t ws_size,
                              hipStream_t stream) {
  const float* x    = (const float*)d_in[0];
  const float* Wqkv = (const float*)d_in[1];
  const float* bqkv = (const float*)d_in[2];
  const float* Wout = (const float*)d_in[3];
  const float* bout = (const float*)d_in[4];
  float* out = (float*)d_out;
  char* wsb = (char*)d_ws;

  unsigned short* qhp  = (unsigned short*)d_ws;
  unsigned short* khp  = qhp + 1 * 4194304;
  unsigned short* klp  = qhp + 2 * 4194304;
  unsigned short* vthp = qhp + 3 * 4194304;
  unsigned short* vals = qhp + 4 * 4194304;
  unsigned short* pO   = (unsigned short*)(wsb + (40u << 20));  // 16 MB
  float*          pl   = (float*)(wsb + (56u << 20));           // 512 KB
  unsigned short* wqh  = (unsigned short*)(wsb + (48u << 20));
  unsigned short* wql  = (unsigned short*)(wsb + (54u << 20));
  unsigned short* woh  = (unsigned short*)(wsb + (60u << 20));
  unsigned short* wol  = (unsigned short*)(wsb + (62u << 20));
  unsigned short* xh   = (unsigned short*)d_out;

  dim3 blk(256);
  split_all<<<8192, blk, 0, stream>>>(x, xh, Wqkv, wqh, wql, Wout, woh, wol);
  gemm_qkv<<<dim3(32, 24), blk, 0, stream>>>(xh, wqh, wql, bqkv,
                                             qhp, khp, klp, vthp);
  attn_ks<<<dim3(32, 16, 2), blk, 0, stream>>>(qhp, khp, klp, vthp, pO, pl);
  merge_vals<<<4096, blk, 0, stream>>>(pO, pl, vals);
  gemm_out2<<<dim3(32, 16), blk, 0, stream>>>(vals, woh, wol, bout, out);
}

// Round 13
// 229.606 us; speedup vs baseline: 1.4391x; 1.0116x over previous
//
#include <hip/hip_runtime.h>
#include <hip/hip_bf16.h>
#include <math.h>

#define Bb 2
#define Ss 2048
#define Ee 1024
#define Hh 16
#define HDd 64
#define NEG_INF_F -1000000000.0f

typedef __attribute__((ext_vector_type(8))) short bfrag;     // 8 bf16
typedef __attribute__((ext_vector_type(4))) float ffrag;     // 16x16 C/D
typedef __attribute__((ext_vector_type(16))) float ffrag16;  // 32x32 C/D
typedef __attribute__((ext_vector_type(8))) unsigned short us8;

#define C1F 0.1803368801f  /* 0.125 * log2(e) — folded into Q at gemm_qkv */

// ---- bf16 helpers ----------------------------------------------------------
__device__ __forceinline__ unsigned short f2bf(float x) {
  unsigned u = __float_as_uint(x);
  u += 0x7fffu + ((u >> 16) & 1u);
  return (unsigned short)(u >> 16);
}
__device__ __forceinline__ float bf2f(unsigned short h) {
  return __uint_as_float(((unsigned)h) << 16);
}

__device__ __forceinline__ void async_copy16(void* lds, const void* g) {
  __builtin_amdgcn_global_load_lds(
      (const __attribute__((address_space(1))) unsigned int*)g,
      (__attribute__((address_space(3))) unsigned int*)lds, 16, 0, 0);
}

// ---------------------------------------------------------------------------
// Fused split pass: x (4M) -> hi only; Wqkv (3M), Wout (1M) -> hi/lo.
// ---------------------------------------------------------------------------
__global__ __launch_bounds__(256) void split_all(
    const float* __restrict__ x, unsigned short* __restrict__ xh,
    const float* __restrict__ wq, unsigned short* __restrict__ wqh,
    unsigned short* __restrict__ wql,
    const float* __restrict__ wo, unsigned short* __restrict__ woh,
    unsigned short* __restrict__ wol) {
  int bid = blockIdx.x;
  const float* in;
  unsigned short *hi, *lo;
  if (bid < 4096) { in = x; hi = xh; lo = nullptr; }
  else if (bid < 7168) { bid -= 4096; in = wq; hi = wqh; lo = wql; }
  else { bid -= 7168; in = wo; hi = woh; lo = wol; }
  const int idx = (bid * 256 + threadIdx.x) * 4;
  const float4 v = *(const float4*)(in + idx);
  unsigned short h0 = f2bf(v.x), h1 = f2bf(v.y), h2 = f2bf(v.z), h3 = f2bf(v.w);
  ushort4 hv = {h0, h1, h2, h3};
  *(ushort4*)(hi + idx) = hv;
  if (lo) {
    ushort4 lv = {f2bf(v.x - bf2f(h0)), f2bf(v.y - bf2f(h1)),
                  f2bf(v.z - bf2f(h2)), f2bf(v.w - bf2f(h3))};
    *(ushort4*)(lo + idx) = lv;
  }
}

// ---------------------------------------------------------------------------
// LDS slot map (rows of 32 bf16 = 4 x 16B chunks):
// slot(row,q) = (row>>1)*8 + ((((row&1)*4)|q) ^ ((row>>1)&7)).
// ---------------------------------------------------------------------------
__device__ __forceinline__ int gemm_slot(int row, int q) {
  return (row >> 1) * 8 + ((((row & 1) * 4) | q) ^ ((row >> 1) & 7));
}
__device__ __forceinline__ int slot_src_off(int slot, int ld) {
  const int dr = slot >> 3;
  const int idx8 = (slot & 7) ^ (dr & 7);
  const int row = dr * 2 + (idx8 >> 2);
  const int q = idx8 & 3;
  return row * ld + q * 8;
}

// ---------------------------------------------------------------------------
// QKV GEMM, 32x32x16 core: C = xh * (Wh + Wl)^T + bias (2 MFMAs/product).
// 128x128 tile. Epilogue: Q single bf16 pre-scaled by C1F -> [bh][s][64];
// K hi/lo -> [bh][s][64]; V single bf16 transposed -> [bh][d][s].
// ---------------------------------------------------------------------------
__global__ __launch_bounds__(256) void gemm_qkv(
    const unsigned short* __restrict__ Ah,
    const unsigned short* __restrict__ Bh, const unsigned short* __restrict__ Bl,
    const float* __restrict__ bias,
    unsigned short* __restrict__ q_h,
    unsigned short* __restrict__ k_h, unsigned short* __restrict__ k_l,
    unsigned short* __restrict__ vt_h) {
  __shared__ unsigned short sm[3 * 4096];
  const int tid = threadIdx.x;
  const int lane = tid & 63;
  const int w = tid >> 6;
  const int wm = w >> 1;
  const int wn = w & 1;
  const int l31 = lane & 31;
  const int e = lane >> 5;
  const int m0 = blockIdx.x * 128;
  const int n0 = blockIdx.y * 128;

  int coff[2], ldsb[2];
#pragma unroll
  for (int u = 0; u < 2; ++u) {
    const int slot = w * 128 + u * 64 + lane;
    coff[u] = slot_src_off(slot, 1024);
    ldsb[u] = (w * 128 + u * 64) * 8;
  }
  const unsigned short* srcs[3] = {
      Ah + (size_t)m0 * 1024, Bh + (size_t)n0 * 1024, Bl + (size_t)n0 * 1024};

  ffrag16 acc[2][2];
#pragma unroll
  for (int i = 0; i < 2; ++i)
#pragma unroll
    for (int j = 0; j < 2; ++j) acc[i][j] = (ffrag16)0.f;

  int ca[2][2], cb[2][2];
#pragma unroll
  for (int t = 0; t < 2; ++t)
#pragma unroll
    for (int h2 = 0; h2 < 2; ++h2) {
      ca[t][h2] = gemm_slot(wm * 64 + t * 32 + l31, h2 * 2 + e) * 8;
      cb[t][h2] = gemm_slot(wn * 64 + t * 32 + l31, h2 * 2 + e) * 8;
    }

  for (int k0 = 0; k0 < 1024; k0 += 32) {
    __syncthreads();
#pragma unroll
    for (int t = 0; t < 3; ++t)
#pragma unroll
      for (int u = 0; u < 2; ++u)
        async_copy16(&sm[t * 4096 + ldsb[u]], srcs[t] + coff[u] + k0);
    __syncthreads();

    bfrag ah[2][2], bhf[2][2], blf[2][2];
#pragma unroll
    for (int t = 0; t < 2; ++t)
#pragma unroll
      for (int h2 = 0; h2 < 2; ++h2) {
        ah[t][h2] = *(const bfrag*)&sm[0 * 4096 + ca[t][h2]];
        bhf[t][h2] = *(const bfrag*)&sm[1 * 4096 + cb[t][h2]];
        blf[t][h2] = *(const bfrag*)&sm[2 * 4096 + cb[t][h2]];
      }
#pragma unroll
    for (int mt = 0; mt < 2; ++mt)
#pragma unroll
      for (int nt = 0; nt < 2; ++nt)
#pragma unroll
        for (int h2 = 0; h2 < 2; ++h2) {
          acc[mt][nt] = __builtin_amdgcn_mfma_f32_32x32x16_bf16(
              ah[mt][h2], bhf[nt][h2], acc[mt][nt], 0, 0, 0);
          acc[mt][nt] = __builtin_amdgcn_mfma_f32_32x32x16_bf16(
              ah[mt][h2], blf[nt][h2], acc[mt][nt], 0, 0, 0);
        }
  }

#pragma unroll
  for (int nt = 0; nt < 2; ++nt) {
    const int n = n0 + wn * 64 + nt * 32 + l31;
    const float bv = bias[n];
    const int h = n / 192;
    const int c = n - h * 192;
    const int d = c & 63;
#pragma unroll
    for (int mt = 0; mt < 2; ++mt) {
      if (c >= 128) {
#pragma unroll
        for (int g = 0; g < 4; ++g) {
          const int m = m0 + wm * 64 + mt * 32 + g * 8 + e * 4;
          const int bidx = m >> 11;
          const int s = m & 2047;
          ushort4 hv4;
          unsigned short* ph = (unsigned short*)&hv4;
#pragma unroll
          for (int r = 0; r < 4; ++r)
            ph[r] = f2bf(acc[mt][nt][g * 4 + r] + bv);
          const size_t off =
              (size_t)(bidx * 16 + h) * (64 * 2048) + (size_t)d * 2048 + s;
          *(ushort4*)(vt_h + off) = hv4;
        }
      } else if (c < 64) {
#pragma unroll
        for (int g = 0; g < 4; ++g)
#pragma unroll
          for (int r = 0; r < 4; ++r) {
            const int m = m0 + wm * 64 + mt * 32 + g * 8 + e * 4 + r;
            const int bidx = m >> 11;
            const int s = m & 2047;
            const size_t off =
                (size_t)(bidx * 16 + h) * (2048 * 64) + (size_t)s * 64 + d;
            q_h[off] = f2bf((acc[mt][nt][g * 4 + r] + bv) * C1F);
          }
      } else {
#pragma unroll
        for (int g = 0; g < 4; ++g)
#pragma unroll
          for (int r = 0; r < 4; ++r) {
            const int m = m0 + wm * 64 + mt * 32 + g * 8 + e * 4 + r;
            const int bidx = m >> 11;
            const int s = m & 2047;
            const float val = acc[mt][nt][g * 4 + r] + bv;
            const unsigned short hv = f2bf(val);
            const size_t off =
                (size_t)(bidx * 16 + h) * (2048 * 64) + (size_t)s * 64 + d;
            k_h[off] = hv;
            k_l[off] = f2bf(val - bf2f(hv));
          }
      }
    }
  }
}

// ---------------------------------------------------------------------------
// Out-proj GEMM: A = vals single bf16, B = Wout hi/lo (2 MFMAs/product).
// 128x64 tile, 512 blocks. Writes fp32+bias directly to out.
// ---------------------------------------------------------------------------
__global__ __launch_bounds__(256) void gemm_out2(
    const unsigned short* __restrict__ A,
    const unsigned short* __restrict__ Bh, const unsigned short* __restrict__ Bl,
    const float* __restrict__ bias, float* __restrict__ out) {
  __shared__ unsigned short sm[8192];
  const int tid = threadIdx.x;
  const int lane = tid & 63;
  const int w = tid >> 6;
  const int wm = w >> 1;
  const int wn = w & 1;
  const int l31 = lane & 31;
  const int e = lane >> 5;
  const int m0 = blockIdx.x * 128;
  const int n0 = blockIdx.y * 64;

  int acoff[2], aldsb[2];
#pragma unroll
  for (int u = 0; u < 2; ++u) {
    const int slot = w * 128 + u * 64 + lane;
    acoff[u] = slot_src_off(slot, 1024);
    aldsb[u] = (w * 128 + u * 64) * 8;
  }
  const int bslot = w * 64 + lane;
  const int bcoff = slot_src_off(bslot, 1024);
  const int bldsb = bslot * 8;

  const unsigned short* Ap  = A + (size_t)m0 * 1024;
  const unsigned short* Bph = Bh + (size_t)n0 * 1024;
  const unsigned short* Bpl = Bl + (size_t)n0 * 1024;

  ffrag16 acc[2];
  acc[0] = (ffrag16)0.f;
  acc[1] = (ffrag16)0.f;

  int ca[2][2], cb[2];
#pragma unroll
  for (int t = 0; t < 2; ++t)
#pragma unroll
    for (int h2 = 0; h2 < 2; ++h2)
      ca[t][h2] = gemm_slot(wm * 64 + t * 32 + l31, h2 * 2 + e) * 8;
#pragma unroll
  for (int h2 = 0; h2 < 2; ++h2)
    cb[h2] = gemm_slot(wn * 32 + l31, h2 * 2 + e) * 8;

  for (int k0 = 0; k0 < 1024; k0 += 32) {
    __syncthreads();
#pragma unroll
    for (int u = 0; u < 2; ++u)
      async_copy16(&sm[0 + aldsb[u]], Ap + acoff[u] + k0);
    async_copy16(&sm[4096 + bldsb], Bph + bcoff + k0);
    async_copy16(&sm[6144 + bldsb], Bpl + bcoff + k0);
    __syncthreads();

    bfrag ah[2][2], bhf[2], blf[2];
#pragma unroll
    for (int t = 0; t < 2; ++t)
#pragma unroll
      for (int h2 = 0; h2 < 2; ++h2)
        ah[t][h2] = *(const bfrag*)&sm[0 + ca[t][h2]];
#pragma unroll
    for (int h2 = 0; h2 < 2; ++h2) {
      bhf[h2] = *(const bfrag*)&sm[4096 + cb[h2]];
      blf[h2] = *(const bfrag*)&sm[6144 + cb[h2]];
    }
#pragma unroll
    for (int mt = 0; mt < 2; ++mt)
#pragma unroll
      for (int h2 = 0; h2 < 2; ++h2) {
        acc[mt] = __builtin_amdgcn_mfma_f32_32x32x16_bf16(
            ah[mt][h2], bhf[h2], acc[mt], 0, 0, 0);
        acc[mt] = __builtin_amdgcn_mfma_f32_32x32x16_bf16(
            ah[mt][h2], blf[h2], acc[mt], 0, 0, 0);
      }
  }

  const int n = n0 + wn * 32 + l31;
  const float bv = bias[n];
#pragma unroll
  for (int mt = 0; mt < 2; ++mt)
#pragma unroll
    for (int g = 0; g < 4; ++g)
#pragma unroll
      for (int r = 0; r < 4; ++r) {
        const int m = m0 + wm * 64 + mt * 32 + g * 8 + e * 4 + r;
        out[(size_t)m * 1024 + n] = acc[mt][g * 4 + r] + bv;
      }
}

// ---------------------------------------------------------------------------
// 8-wave split-K balanced MFMA flash attention. Block (bh, j, z), 512 thr:
// waves 0-3 serve y=2j, waves 4-7 serve y=2j+1 (per wave: 16 A-rows of y and
// 16 B-rows of 31-y). One 24KB K/V stage feeds 8 waves (half the DMA/CU of
// the 4-wave version); double-buffered (48KB) + P 32KB = 81920 B -> exactly
// 2 blocks/CU = 16 waves/CU (R8 precedent: exact-160KiB fits).
// z-split: z0 kt in [2j, j+16), z1 [j+16, 32) -> 16-j iters each (balanced).
// Fixed-max softmax => O,l plain sums => split is associative; RAW partials
// (bf16 O + fp32 l) merged by merge_vals. Math identical to R12 per wave.
// ---------------------------------------------------------------------------
__global__ __launch_bounds__(512) void attn_ks8(
    const unsigned short* __restrict__ qh,
    const unsigned short* __restrict__ kh, const unsigned short* __restrict__ kl,
    const unsigned short* __restrict__ vth,
    unsigned short* __restrict__ pO, float* __restrict__ pl) {
  __shared__ unsigned short sm[2 * 12288 + 16384];  // dbuf (Kh|Kl|Vh) + P 32KB
  const int tid = threadIdx.x;
  const int lane = tid & 63;
  const int w = tid >> 6;        // 0..7
  const int wl = w & 3;          // wave index within its y-group
  const int l15 = lane & 15;
  const int quad = lane >> 4;
  const int bh = blockIdx.x;
  const int j = blockIdx.y;      // 0..7
  const int z = blockIdx.z;
  const int yw = 2 * j + (w >> 2);
  const int rbase[2] = {64 * yw + 16 * wl, 64 * (31 - yw) + 16 * wl};
  const int ktB = 31 - yw;
  const int kts = z ? (j + 16) : (2 * j);
  const int kte = z ? 32 : (j + 16);
  const bool fix = (yw == 0) && (wl == 3);  // w==3: owns row 2047
  const size_t base = (size_t)bh * (Ss * HDd);
  const int PB = 24576;  // P region base (shorts), 256 rows x 64

  bfrag Qh[2][2];
#pragma unroll
  for (int mt = 0; mt < 2; ++mt)
#pragma unroll
    for (int ks = 0; ks < 2; ++ks) {
      const size_t off = base + (size_t)(rbase[mt] + l15) * 64 + ks * 32 + quad * 8;
      Qh[mt][ks] = *(const bfrag*)(qh + off);
    }

  bfrag vone;
#pragma unroll
  for (int jj = 0; jj < 8; ++jj) vone[jj] = (short)0x3F80;  // bf16 1.0

  // staging: each of 8 waves stages 64 chunks (1KB) per buffer
  const int c0 = w * 64 + lane;
  const int r0 = c0 >> 3;
  const int s0 = ((c0 & 7) ^ (r0 & 7)) * 8;
  const int koff0 = r0 * 64 + s0;
  const int voff0 = r0 * 2048 + s0;
  const int ldsc0 = (w * 64) * 8;

  ffrag O[2][4], Oe[2], Vsum[4];
#pragma unroll
  for (int mt = 0; mt < 2; ++mt) {
#pragma unroll
    for (int dt = 0; dt < 4; ++dt) O[mt][dt] = (ffrag)0.f;
    Oe[mt] = (ffrag)0.f;
  }
#pragma unroll
  for (int dt = 0; dt < 4; ++dt) Vsum[dt] = (ffrag)0.f;

  {  // prologue: stage kts into set 0
    async_copy16(&sm[0 + ldsc0], kh + base + kts * 4096 + koff0);
    async_copy16(&sm[4096 + ldsc0], kl + base + kts * 4096 + koff0);
    async_copy16(&sm[8192 + ldsc0], vth + base + kts * 64 + voff0);
  }

  int bufo = 0;  // 0 or 12288
  for (int kt = kts; kt < kte; ++kt) {
    __syncthreads();  // drains DMA for cur set; prior reads of alt done
    if (kt + 1 < kte) {
      const int alt = bufo ^ 12288;
      async_copy16(&sm[alt + 0 + ldsc0], kh + base + (kt + 1) * 4096 + koff0);
      async_copy16(&sm[alt + 4096 + ldsc0], kl + base + (kt + 1) * 4096 + koff0);
      async_copy16(&sm[alt + 8192 + ldsc0], vth + base + (kt + 1) * 64 + voff0);
    }
    const bool aact = (kt >= yw);   // only false for odd-y waves at kt=2j
    const bool bact = (kt >= ktB);

    // ---- S = Q K^T (Q pre-scaled; K = Kh + Kl)
    ffrag S[2][4];
#pragma unroll
    for (int mt = 0; mt < 2; ++mt)
#pragma unroll
      for (int nt = 0; nt < 4; ++nt) S[mt][nt] = (ffrag)0.f;
#pragma unroll
    for (int nt = 0; nt < 4; ++nt) {
      const int krow = nt * 16 + l15;
#pragma unroll
      for (int ks = 0; ks < 2; ++ks) {
        const int koffr = bufo + krow * 64 + ((ks * 4 + quad) ^ (krow & 7)) * 8;
        const bfrag kbh = *(const bfrag*)&sm[koffr];
        const bfrag kbl = *(const bfrag*)&sm[4096 + koffr];
        if (aact) {
          S[0][nt] = __builtin_amdgcn_mfma_f32_16x16x32_bf16(Qh[0][ks], kbh, S[0][nt], 0, 0, 0);
          S[0][nt] = __builtin_amdgcn_mfma_f32_16x16x32_bf16(Qh[0][ks], kbl, S[0][nt], 0, 0, 0);
        }
        if (bact) {
          S[1][nt] = __builtin_amdgcn_mfma_f32_16x16x32_bf16(Qh[1][ks], kbh, S[1][nt], 0, 0, 0);
          S[1][nt] = __builtin_amdgcn_mfma_f32_16x16x32_bf16(Qh[1][ks], kbl, S[1][nt], 0, 0, 0);
        }
      }
    }

    // ---- p = exp2(S [+ CM if masked]); packed bf16 cvt; store to P LDS
    const float CM = -1.442695041e9f;  // -1e9 * log2(e)
#pragma unroll
    for (int mt = 0; mt < 2; ++mt) {
      if (mt == 0 && !aact) continue;
      if (mt == 1 && !bact) continue;
      const bool partial = (kt == (mt == 0 ? yw : ktB));
#pragma unroll
      for (int nt = 0; nt < 4; ++nt) {
        const int key = nt * 16 + l15;
#pragma unroll
        for (int rp = 0; rp < 2; ++rp) {
          float t0 = S[mt][nt][2 * rp];
          float t1 = S[mt][nt][2 * rp + 1];
          if (partial) {
            const int jg = kt * 64 + key;
            const int ig = rbase[mt] + quad * 4 + 2 * rp;
            if (jg <= ig) t0 += CM;
            if (jg <= ig + 1) t1 += CM;
          }
          float2 pf;
          pf.x = __builtin_amdgcn_exp2f(t0);
          pf.y = __builtin_amdgcn_exp2f(t1);
          const __hip_bfloat162 pb = __float22bfloat162_rn(pf);
          const unsigned short* pbs = (const unsigned short*)&pb;
          const int prow0 = w * 32 + mt * 16 + quad * 4 + 2 * rp;
          sm[PB + prow0 * 64 + (((key >> 3) ^ (prow0 & 7)) * 8 + (key & 7))] = pbs[0];
          const int prow1 = prow0 + 1;
          sm[PB + prow1 * 64 + (((key >> 3) ^ (prow1 & 7)) * 8 + (key & 7))] = pbs[1];
        }
      }
    }

    // ---- PV (V single) + l via ones-MFMA (+ Vsum on the fix wave)
#pragma unroll
    for (int ks = 0; ks < 2; ++ks) {
      bfrag pA[2];
#pragma unroll
      for (int mt = 0; mt < 2; ++mt) {
        if (mt == 0 && !aact) continue;
        if (mt == 1 && !bact) continue;
        const int prow = w * 32 + mt * 16 + l15;
        pA[mt] = *(const bfrag*)&sm[PB + prow * 64 + ((ks * 4 + quad) ^ (prow & 7)) * 8];
      }
      if (aact)
        Oe[0] = __builtin_amdgcn_mfma_f32_16x16x32_bf16(pA[0], vone, Oe[0], 0, 0, 0);
      if (bact)
        Oe[1] = __builtin_amdgcn_mfma_f32_16x16x32_bf16(pA[1], vone, Oe[1], 0, 0, 0);
#pragma unroll
      for (int dt = 0; dt < 4; ++dt) {
        const int vrow = dt * 16 + l15;
        const int voffr = bufo + 8192 + vrow * 64 + ((ks * 4 + quad) ^ (vrow & 7)) * 8;
        const bfrag vbh = *(const bfrag*)&sm[voffr];
        if (aact)
          O[0][dt] = __builtin_amdgcn_mfma_f32_16x16x32_bf16(pA[0], vbh, O[0][dt], 0, 0, 0);
        if (bact)
          O[1][dt] = __builtin_amdgcn_mfma_f32_16x16x32_bf16(pA[1], vbh, O[1][dt], 0, 0, 0);
        if (fix)
          Vsum[dt] = __builtin_amdgcn_mfma_f32_16x16x32_bf16(vone, vbh, Vsum[dt], 0, 0, 0);
      }
    }
    bufo ^= 12288;
  }

  // ---- epilogue: RAW partials. pO[z][bh][s][d] bf16, pl[z][bh*2048+s] f32.
  // Row 2047: masked path sums to 0 -> substitute partial Vsum + key count;
  // merge then yields mean(V) exactly.
  const size_t pbase = (size_t)z * (32 * 2048 * 64) + (size_t)bh * (2048 * 64);
  const int lbase = z * 65536 + bh * 2048;
  const float lfix = 64.0f * (float)(kte - kts);
#pragma unroll
  for (int mt = 0; mt < 2; ++mt)
#pragma unroll
    for (int r = 0; r < 4; ++r) {
      const int s = rbase[mt] + quad * 4 + r;
      const bool fl = fix && mt == 1 && quad == 3 && r == 3;  // s == 2047
#pragma unroll
      for (int dt = 0; dt < 4; ++dt) {
        const float val = fl ? Vsum[dt][r] : O[mt][dt][r];
        pO[pbase + (size_t)s * 64 + dt * 16 + l15] = f2bf(val);
      }
      if (l15 == 0) pl[lbase + s] = fl ? lfix : Oe[mt][r];
    }
}

// ---------------------------------------------------------------------------
// Merge: vals[b][s][h*64+d] = bf16( (O0+O1) / (l0+l1) ). 4M elems.
// ---------------------------------------------------------------------------
__global__ __launch_bounds__(256) void merge_vals(
    const unsigned short* __restrict__ pO, const float* __restrict__ pl,
    unsigned short* __restrict__ vals) {
  const int idx = (blockIdx.x * 256 + threadIdx.x) * 4;
  const int d = idx & 63;
  const int sbh = idx >> 6;       // bh*2048 + s
  const int s = sbh & 2047;
  const int bh = sbh >> 11;
  const size_t zstr = (size_t)32 * 2048 * 64;
  const ushort4 o0 = *(const ushort4*)(pO + (size_t)sbh * 64 + d);
  const ushort4 o1 = *(const ushort4*)(pO + zstr + (size_t)sbh * 64 + d);
  const float inv = 1.0f / (pl[sbh] + pl[65536 + sbh]);
  ushort4 rv;
  rv.x = f2bf((bf2f(o0.x) + bf2f(o1.x)) * inv);
  rv.y = f2bf((bf2f(o0.y) + bf2f(o1.y)) * inv);
  rv.z = f2bf((bf2f(o0.z) + bf2f(o1.z)) * inv);
  rv.w = f2bf((bf2f(o0.w) + bf2f(o1.w)) * inv);
  const int b = bh >> 4;
  const int h = bh & 15;
  *(ushort4*)(vals + ((size_t)b * 2048 + s) * 1024 + h * 64 + d) = rv;
}

// ---------------------------------------------------------------------------
// ws (64 MB): qh[0,8) kh[8,16) kl[16,24) vth[24,32) vals[32,40)
// pO[40,56) pl[56,56.5)   (pO/pl overlay dead wq region)
// wqh[48,54) wql[54,60) woh[60,62) wol[62,64)  (wq dead after gemm_qkv).
// d_out: xh[0,8) (dead after gemm_qkv); gemm_out2 writes final fp32 directly.
// ---------------------------------------------------------------------------
extern "C" void kernel_launch(void* const* d_in, const int* in_sizes, int n_in,
                              void* d_out, int out_size, void* d_ws, size_t ws_size,
                              hipStream_t stream) {
  const float* x    = (const float*)d_in[0];
  const float* Wqkv = (const float*)d_in[1];
  const float* bqkv = (const float*)d_in[2];
  const float* Wout = (const float*)d_in[3];
  const float* bout = (const float*)d_in[4];
  float* out = (float*)d_out;
  char* wsb = (char*)d_ws;

  unsigned short* qhp  = (unsigned short*)d_ws;
  unsigned short* khp  = qhp + 1 * 4194304;
  unsigned short* klp  = qhp + 2 * 4194304;
  unsigned short* vthp = qhp + 3 * 4194304;
  unsigned short* vals = qhp + 4 * 4194304;
  unsigned short* pO   = (unsigned short*)(wsb + (40u << 20));  // 16 MB
  float*          pl   = (float*)(wsb + (56u << 20));           // 512 KB
  unsigned short* wqh  = (unsigned short*)(wsb + (48u << 20));
  unsigned short* wql  = (unsigned short*)(wsb + (54u << 20));
  unsigned short* woh  = (unsigned short*)(wsb + (60u << 20));
  unsigned short* wol  = (unsigned short*)(wsb + (62u << 20));
  unsigned short* xh   = (unsigned short*)d_out;

  dim3 blk(256);
  split_all<<<8192, blk, 0, stream>>>(x, xh, Wqkv, wqh, wql, Wout, woh, wol);
  gemm_qkv<<<dim3(32, 24), blk, 0, stream>>>(xh, wqh, wql, bqkv,
                                             qhp, khp, klp, vthp);
  attn_ks8<<<dim3(32, 8, 2), dim3(512), 0, stream>>>(qhp, khp, klp, vthp, pO, pl);
  merge_vals<<<4096, blk, 0, stream>>>(pO, pl, vals);
  gemm_out2<<<dim3(32, 16), blk, 0, stream>>>(vals, woh, wol, bout, out);
}

// Round 14
// 221.541 us; speedup vs baseline: 1.4915x; 1.0364x over previous
//
#include <hip/hip_runtime.h>
#include <hip/hip_bf16.h>
#include <math.h>

#define Bb 2
#define Ss 2048
#define Ee 1024
#define Hh 16
#define HDd 64
#define NEG_INF_F -1000000000.0f

typedef __attribute__((ext_vector_type(8))) short bfrag;     // 8 bf16
typedef __attribute__((ext_vector_type(4))) float ffrag;     // 16x16 C/D
typedef __attribute__((ext_vector_type(16))) float ffrag16;  // 32x32 C/D
typedef __attribute__((ext_vector_type(8))) unsigned short us8;

#define C1F 0.1803368801f  /* 0.125 * log2(e) — folded into Q at gemm_qkv */

// ---- bf16 helpers ----------------------------------------------------------
__device__ __forceinline__ unsigned short f2bf(float x) {
  unsigned u = __float_as_uint(x);
  u += 0x7fffu + ((u >> 16) & 1u);
  return (unsigned short)(u >> 16);
}
__device__ __forceinline__ float bf2f(unsigned short h) {
  return __uint_as_float(((unsigned)h) << 16);
}

__device__ __forceinline__ void async_copy16(void* lds, const void* g) {
  __builtin_amdgcn_global_load_lds(
      (const __attribute__((address_space(1))) unsigned int*)g,
      (__attribute__((address_space(3))) unsigned int*)lds, 16, 0, 0);
}

// ---------------------------------------------------------------------------
// Fused split pass: x (4M) -> hi only; Wqkv (3M), Wout (1M) -> hi/lo.
// ---------------------------------------------------------------------------
__global__ __launch_bounds__(256) void split_all(
    const float* __restrict__ x, unsigned short* __restrict__ xh,
    const float* __restrict__ wq, unsigned short* __restrict__ wqh,
    unsigned short* __restrict__ wql,
    const float* __restrict__ wo, unsigned short* __restrict__ woh,
    unsigned short* __restrict__ wol) {
  int bid = blockIdx.x;
  const float* in;
  unsigned short *hi, *lo;
  if (bid < 4096) { in = x; hi = xh; lo = nullptr; }
  else if (bid < 7168) { bid -= 4096; in = wq; hi = wqh; lo = wql; }
  else { bid -= 7168; in = wo; hi = woh; lo = wol; }
  const int idx = (bid * 256 + threadIdx.x) * 4;
  const float4 v = *(const float4*)(in + idx);
  unsigned short h0 = f2bf(v.x), h1 = f2bf(v.y), h2 = f2bf(v.z), h3 = f2bf(v.w);
  ushort4 hv = {h0, h1, h2, h3};
  *(ushort4*)(hi + idx) = hv;
  if (lo) {
    ushort4 lv = {f2bf(v.x - bf2f(h0)), f2bf(v.y - bf2f(h1)),
                  f2bf(v.z - bf2f(h2)), f2bf(v.w - bf2f(h3))};
    *(ushort4*)(lo + idx) = lv;
  }
}

// ---------------------------------------------------------------------------
// LDS slot map (rows of 32 bf16 = 4 x 16B chunks):
// slot(row,q) = (row>>1)*8 + ((((row&1)*4)|q) ^ ((row>>1)&7)).
// ---------------------------------------------------------------------------
__device__ __forceinline__ int gemm_slot(int row, int q) {
  return (row >> 1) * 8 + ((((row & 1) * 4) | q) ^ ((row >> 1) & 7));
}
__device__ __forceinline__ int slot_src_off(int slot, int ld) {
  const int dr = slot >> 3;
  const int idx8 = (slot & 7) ^ (dr & 7);
  const int row = dr * 2 + (idx8 >> 2);
  const int q = idx8 & 3;
  return row * ld + q * 8;
}

// ---------------------------------------------------------------------------
// QKV GEMM, 32x32x16 core: C = xh * (Wh + Wl)^T + bias (2 MFMAs/product).
// 128x128 tile. Epilogue (all SINGLE bf16 now — K_lo dropped; error math:
// delta(p)/p ~ 0.0014 < bf16-P rounding 2^-9 which dominates absmax):
// Q pre-scaled by C1F -> [bh][s][64]; K -> [bh][s][64]; V^T -> [bh][d][s].
// ---------------------------------------------------------------------------
__global__ __launch_bounds__(256) void gemm_qkv(
    const unsigned short* __restrict__ Ah,
    const unsigned short* __restrict__ Bh, const unsigned short* __restrict__ Bl,
    const float* __restrict__ bias,
    unsigned short* __restrict__ q_h, unsigned short* __restrict__ k_h,
    unsigned short* __restrict__ vt_h) {
  __shared__ unsigned short sm[3 * 4096];
  const int tid = threadIdx.x;
  const int lane = tid & 63;
  const int w = tid >> 6;
  const int wm = w >> 1;
  const int wn = w & 1;
  const int l31 = lane & 31;
  const int e = lane >> 5;
  const int m0 = blockIdx.x * 128;
  const int n0 = blockIdx.y * 128;

  int coff[2], ldsb[2];
#pragma unroll
  for (int u = 0; u < 2; ++u) {
    const int slot = w * 128 + u * 64 + lane;
    coff[u] = slot_src_off(slot, 1024);
    ldsb[u] = (w * 128 + u * 64) * 8;
  }
  const unsigned short* srcs[3] = {
      Ah + (size_t)m0 * 1024, Bh + (size_t)n0 * 1024, Bl + (size_t)n0 * 1024};

  ffrag16 acc[2][2];
#pragma unroll
  for (int i = 0; i < 2; ++i)
#pragma unroll
    for (int j = 0; j < 2; ++j) acc[i][j] = (ffrag16)0.f;

  int ca[2][2], cb[2][2];
#pragma unroll
  for (int t = 0; t < 2; ++t)
#pragma unroll
    for (int h2 = 0; h2 < 2; ++h2) {
      ca[t][h2] = gemm_slot(wm * 64 + t * 32 + l31, h2 * 2 + e) * 8;
      cb[t][h2] = gemm_slot(wn * 64 + t * 32 + l31, h2 * 2 + e) * 8;
    }

  for (int k0 = 0; k0 < 1024; k0 += 32) {
    __syncthreads();
#pragma unroll
    for (int t = 0; t < 3; ++t)
#pragma unroll
      for (int u = 0; u < 2; ++u)
        async_copy16(&sm[t * 4096 + ldsb[u]], srcs[t] + coff[u] + k0);
    __syncthreads();

    bfrag ah[2][2], bhf[2][2], blf[2][2];
#pragma unroll
    for (int t = 0; t < 2; ++t)
#pragma unroll
      for (int h2 = 0; h2 < 2; ++h2) {
        ah[t][h2] = *(const bfrag*)&sm[0 * 4096 + ca[t][h2]];
        bhf[t][h2] = *(const bfrag*)&sm[1 * 4096 + cb[t][h2]];
        blf[t][h2] = *(const bfrag*)&sm[2 * 4096 + cb[t][h2]];
      }
#pragma unroll
    for (int mt = 0; mt < 2; ++mt)
#pragma unroll
      for (int nt = 0; nt < 2; ++nt)
#pragma unroll
        for (int h2 = 0; h2 < 2; ++h2) {
          acc[mt][nt] = __builtin_amdgcn_mfma_f32_32x32x16_bf16(
              ah[mt][h2], bhf[nt][h2], acc[mt][nt], 0, 0, 0);
          acc[mt][nt] = __builtin_amdgcn_mfma_f32_32x32x16_bf16(
              ah[mt][h2], blf[nt][h2], acc[mt][nt], 0, 0, 0);
        }
  }

#pragma unroll
  for (int nt = 0; nt < 2; ++nt) {
    const int n = n0 + wn * 64 + nt * 32 + l31;
    const float bv = bias[n];
    const int h = n / 192;
    const int c = n - h * 192;
    const int d = c & 63;
#pragma unroll
    for (int mt = 0; mt < 2; ++mt) {
      if (c >= 128) {
        // V path (single bf16): reg-group g = 4 consecutive s -> ushort4
#pragma unroll
        for (int g = 0; g < 4; ++g) {
          const int m = m0 + wm * 64 + mt * 32 + g * 8 + e * 4;
          const int bidx = m >> 11;
          const int s = m & 2047;
          ushort4 hv4;
          unsigned short* ph = (unsigned short*)&hv4;
#pragma unroll
          for (int r = 0; r < 4; ++r)
            ph[r] = f2bf(acc[mt][nt][g * 4 + r] + bv);
          const size_t off =
              (size_t)(bidx * 16 + h) * (64 * 2048) + (size_t)d * 2048 + s;
          *(ushort4*)(vt_h + off) = hv4;
        }
      } else {
        // Q (scaled by C1F) / K — both single bf16, [bh][s][64]
        const float scale = (c < 64) ? C1F : 1.0f;
        unsigned short* dh = (c < 64) ? q_h : k_h;
#pragma unroll
        for (int g = 0; g < 4; ++g)
#pragma unroll
          for (int r = 0; r < 4; ++r) {
            const int m = m0 + wm * 64 + mt * 32 + g * 8 + e * 4 + r;
            const int bidx = m >> 11;
            const int s = m & 2047;
            const size_t off =
                (size_t)(bidx * 16 + h) * (2048 * 64) + (size_t)s * 64 + d;
            dh[off] = f2bf((acc[mt][nt][g * 4 + r] + bv) * scale);
          }
      }
    }
  }
}

// ---------------------------------------------------------------------------
// Out-proj GEMM: A = vals single bf16, B = Wout hi/lo (2 MFMAs/product).
// 128x64 tile, 512 blocks. Writes fp32+bias directly to out.
// ---------------------------------------------------------------------------
__global__ __launch_bounds__(256) void gemm_out2(
    const unsigned short* __restrict__ A,
    const unsigned short* __restrict__ Bh, const unsigned short* __restrict__ Bl,
    const float* __restrict__ bias, float* __restrict__ out) {
  __shared__ unsigned short sm[8192];
  const int tid = threadIdx.x;
  const int lane = tid & 63;
  const int w = tid >> 6;
  const int wm = w >> 1;
  const int wn = w & 1;
  const int l31 = lane & 31;
  const int e = lane >> 5;
  const int m0 = blockIdx.x * 128;
  const int n0 = blockIdx.y * 64;

  int acoff[2], aldsb[2];
#pragma unroll
  for (int u = 0; u < 2; ++u) {
    const int slot = w * 128 + u * 64 + lane;
    acoff[u] = slot_src_off(slot, 1024);
    aldsb[u] = (w * 128 + u * 64) * 8;
  }
  const int bslot = w * 64 + lane;
  const int bcoff = slot_src_off(bslot, 1024);
  const int bldsb = bslot * 8;

  const unsigned short* Ap  = A + (size_t)m0 * 1024;
  const unsigned short* Bph = Bh + (size_t)n0 * 1024;
  const unsigned short* Bpl = Bl + (size_t)n0 * 1024;

  ffrag16 acc[2];
  acc[0] = (ffrag16)0.f;
  acc[1] = (ffrag16)0.f;

  int ca[2][2], cb[2];
#pragma unroll
  for (int t = 0; t < 2; ++t)
#pragma unroll
    for (int h2 = 0; h2 < 2; ++h2)
      ca[t][h2] = gemm_slot(wm * 64 + t * 32 + l31, h2 * 2 + e) * 8;
#pragma unroll
  for (int h2 = 0; h2 < 2; ++h2)
    cb[h2] = gemm_slot(wn * 32 + l31, h2 * 2 + e) * 8;

  for (int k0 = 0; k0 < 1024; k0 += 32) {
    __syncthreads();
#pragma unroll
    for (int u = 0; u < 2; ++u)
      async_copy16(&sm[0 + aldsb[u]], Ap + acoff[u] + k0);
    async_copy16(&sm[4096 + bldsb], Bph + bcoff + k0);
    async_copy16(&sm[6144 + bldsb], Bpl + bcoff + k0);
    __syncthreads();

    bfrag ah[2][2], bhf[2], blf[2];
#pragma unroll
    for (int t = 0; t < 2; ++t)
#pragma unroll
      for (int h2 = 0; h2 < 2; ++h2)
        ah[t][h2] = *(const bfrag*)&sm[0 + ca[t][h2]];
#pragma unroll
    for (int h2 = 0; h2 < 2; ++h2) {
      bhf[h2] = *(const bfrag*)&sm[4096 + cb[h2]];
      blf[h2] = *(const bfrag*)&sm[6144 + cb[h2]];
    }
#pragma unroll
    for (int mt = 0; mt < 2; ++mt)
#pragma unroll
      for (int h2 = 0; h2 < 2; ++h2) {
        acc[mt] = __builtin_amdgcn_mfma_f32_32x32x16_bf16(
            ah[mt][h2], bhf[h2], acc[mt], 0, 0, 0);
        acc[mt] = __builtin_amdgcn_mfma_f32_32x32x16_bf16(
            ah[mt][h2], blf[h2], acc[mt], 0, 0, 0);
      }
  }

  const int n = n0 + wn * 32 + l31;
  const float bv = bias[n];
#pragma unroll
  for (int mt = 0; mt < 2; ++mt)
#pragma unroll
    for (int g = 0; g < 4; ++g)
#pragma unroll
      for (int r = 0; r < 4; ++r) {
        const int m = m0 + wm * 64 + mt * 32 + g * 8 + e * 4 + r;
        out[(size_t)m * 1024 + n] = acc[mt][g * 4 + r] + bv;
      }
}

// ---------------------------------------------------------------------------
// Balanced MFMA flash attention (R10 structure), ALL-single-bf16 inputs.
// Block (bh, y): group A rows [64y,+64), B rows [64(31-y),+64); A active
// kt>=y, B kt>=31-y -> exactly 33 MFMA-units/block. Fixed-max softmax
// (Q pre-scaled C1F); p = exp2(S [+ CM]); l via ones-MFMA. Double-buffered
// K/V staging: 2 x (Kh 8KB | Vh 8KB) + P 16KB = 48 KB LDS. Row-2047 fixup
// fused (y==0, w==3 accumulates mean(V) via ones-A MFMAs).
// ---------------------------------------------------------------------------
__global__ __launch_bounds__(256) void attn_pair(
    const unsigned short* __restrict__ qh, const unsigned short* __restrict__ kh,
    const unsigned short* __restrict__ vth, unsigned short* __restrict__ vals) {
  __shared__ unsigned short sm[2 * 8192 + 8192];  // dbuf stage sets + P
  const int tid = threadIdx.x;
  const int lane = tid & 63;
  const int w = tid >> 6;
  const int l15 = lane & 15;
  const int quad = lane >> 4;
  const int bh = blockIdx.x;
  const int y = blockIdx.y;
  const int rbase[2] = {64 * y + 16 * w, 64 * (31 - y) + 16 * w};
  const int ktB = 31 - y;
  const bool fix = (y == 0) && (w == 3);  // owns row 2047; sees all keys
  const size_t base = (size_t)bh * (Ss * HDd);
  const int PB = 16384;  // P region base (shorts)

  bfrag Qh[2][2];
#pragma unroll
  for (int mt = 0; mt < 2; ++mt)
#pragma unroll
    for (int ks = 0; ks < 2; ++ks) {
      const size_t off = base + (size_t)(rbase[mt] + l15) * 64 + ks * 32 + quad * 8;
      Qh[mt][ks] = *(const bfrag*)(qh + off);
    }

  bfrag vone;
#pragma unroll
  for (int j = 0; j < 8; ++j) vone[j] = (short)0x3F80;  // bf16 1.0

  const int c0 = w * 128 + lane;
  const int c1 = c0 + 64;
  const int r0 = c0 >> 3, r1 = c1 >> 3;
  const int s0 = ((c0 & 7) ^ (r0 & 7)) * 8;
  const int s1 = ((c1 & 7) ^ (r1 & 7)) * 8;
  const int koff0 = r0 * 64 + s0, koff1 = r1 * 64 + s1;
  const int voff0 = r0 * 2048 + s0, voff1 = r1 * 2048 + s1;
  const int ldsc0 = (w * 128) * 8;
  const int ldsc1 = (w * 128 + 64) * 8;

  ffrag O[2][4], Oe[2], Vsum[4];
#pragma unroll
  for (int mt = 0; mt < 2; ++mt) {
#pragma unroll
    for (int dt = 0; dt < 4; ++dt) O[mt][dt] = (ffrag)0.f;
    Oe[mt] = (ffrag)0.f;
  }
#pragma unroll
  for (int dt = 0; dt < 4; ++dt) Vsum[dt] = (ffrag)0.f;

  {  // prologue: stage tile y into set 0
    const unsigned short* kph = kh + base + y * 4096;
    const unsigned short* vph = vth + base + y * 64;
    async_copy16(&sm[0 + ldsc0], kph + koff0);
    async_copy16(&sm[0 + ldsc1], kph + koff1);
    async_copy16(&sm[4096 + ldsc0], vph + voff0);
    async_copy16(&sm[4096 + ldsc1], vph + voff1);
  }

  int bufo = 0;  // 0 or 8192 (shorts)
  for (int kt = y; kt < 32; ++kt) {
    __syncthreads();  // drains DMA for cur set (issued a full iter ago)
    if (kt + 1 < 32) {
      const int alt = bufo ^ 8192;
      const unsigned short* kph = kh + base + (kt + 1) * 4096;
      const unsigned short* vph = vth + base + (kt + 1) * 64;
      async_copy16(&sm[alt + 0 + ldsc0], kph + koff0);
      async_copy16(&sm[alt + 0 + ldsc1], kph + koff1);
      async_copy16(&sm[alt + 4096 + ldsc0], vph + voff0);
      async_copy16(&sm[alt + 4096 + ldsc1], vph + voff1);
    }
    const bool bact = (kt >= ktB);

    // ---- S = Q K^T (Q pre-scaled; K single bf16 — 1 MFMA per (nt,ks,mt))
    ffrag S[2][4];
#pragma unroll
    for (int mt = 0; mt < 2; ++mt)
#pragma unroll
      for (int nt = 0; nt < 4; ++nt) S[mt][nt] = (ffrag)0.f;
#pragma unroll
    for (int nt = 0; nt < 4; ++nt) {
      const int krow = nt * 16 + l15;
#pragma unroll
      for (int ks = 0; ks < 2; ++ks) {
        const int koffr = bufo + krow * 64 + ((ks * 4 + quad) ^ (krow & 7)) * 8;
        const bfrag kbh = *(const bfrag*)&sm[koffr];
        S[0][nt] = __builtin_amdgcn_mfma_f32_16x16x32_bf16(Qh[0][ks], kbh, S[0][nt], 0, 0, 0);
        if (bact)
          S[1][nt] = __builtin_amdgcn_mfma_f32_16x16x32_bf16(Qh[1][ks], kbh, S[1][nt], 0, 0, 0);
      }
    }

    // ---- p = exp2(S [+ CM if masked]); packed bf16 cvt; store to P LDS
    const float CM = -1.442695041e9f;  // -1e9 * log2(e)
#pragma unroll
    for (int mt = 0; mt < 2; ++mt) {
      if (mt == 1 && !bact) continue;
      const bool partial = (kt == (mt == 0 ? y : ktB));
#pragma unroll
      for (int nt = 0; nt < 4; ++nt) {
        const int key = nt * 16 + l15;
#pragma unroll
        for (int rp = 0; rp < 2; ++rp) {
          float t0 = S[mt][nt][2 * rp];
          float t1 = S[mt][nt][2 * rp + 1];
          if (partial) {
            const int jg = kt * 64 + key;
            const int ig = rbase[mt] + quad * 4 + 2 * rp;
            if (jg <= ig) t0 += CM;
            if (jg <= ig + 1) t1 += CM;
          }
          float2 pf;
          pf.x = __builtin_amdgcn_exp2f(t0);
          pf.y = __builtin_amdgcn_exp2f(t1);
          const __hip_bfloat162 pb = __float22bfloat162_rn(pf);
          const unsigned short* pbs = (const unsigned short*)&pb;
          const int prow0 = w * 32 + mt * 16 + quad * 4 + 2 * rp;
          sm[PB + prow0 * 64 + (((key >> 3) ^ (prow0 & 7)) * 8 + (key & 7))] = pbs[0];
          const int prow1 = prow0 + 1;
          sm[PB + prow1 * 64 + (((key >> 3) ^ (prow1 & 7)) * 8 + (key & 7))] = pbs[1];
        }
      }
    }

    // ---- PV (V single) + l via ones-MFMA (+ Vsum on the fix wave)
#pragma unroll
    for (int ks = 0; ks < 2; ++ks) {
      bfrag pA[2];
#pragma unroll
      for (int mt = 0; mt < 2; ++mt) {
        if (mt == 1 && !bact) continue;
        const int prow = w * 32 + mt * 16 + l15;
        pA[mt] = *(const bfrag*)&sm[PB + prow * 64 + ((ks * 4 + quad) ^ (prow & 7)) * 8];
      }
      Oe[0] = __builtin_amdgcn_mfma_f32_16x16x32_bf16(pA[0], vone, Oe[0], 0, 0, 0);
      if (bact)
        Oe[1] = __builtin_amdgcn_mfma_f32_16x16x32_bf16(pA[1], vone, Oe[1], 0, 0, 0);
#pragma unroll
      for (int dt = 0; dt < 4; ++dt) {
        const int vrow = dt * 16 + l15;
        const int voffr = bufo + 4096 + vrow * 64 + ((ks * 4 + quad) ^ (vrow & 7)) * 8;
        const bfrag vbh = *(const bfrag*)&sm[voffr];
        O[0][dt] = __builtin_amdgcn_mfma_f32_16x16x32_bf16(pA[0], vbh, O[0][dt], 0, 0, 0);
        if (bact)
          O[1][dt] = __builtin_amdgcn_mfma_f32_16x16x32_bf16(pA[1], vbh, O[1][dt], 0, 0, 0);
        if (fix)
          Vsum[dt] = __builtin_amdgcn_mfma_f32_16x16x32_bf16(vone, vbh, Vsum[dt], 0, 0, 0);
      }
    }
    bufo ^= 8192;
  }

  // ---- epilogue: vals[b][s][h*64+d] single bf16; l = Oe row sum.
  // Row 2047 (fully masked -> exactly uniform) = mean(V), from Vsum.
  const int b = bh >> 4;
  const int h = bh & 15;
#pragma unroll
  for (int mt = 0; mt < 2; ++mt)
#pragma unroll
    for (int r = 0; r < 4; ++r) {
      const float inv = 1.0f / Oe[mt][r];
      const int s = rbase[mt] + quad * 4 + r;
      const size_t rowoff = ((size_t)b * 2048 + s) * 1024 + h * 64;
#pragma unroll
      for (int dt = 0; dt < 4; ++dt) {
        float val = O[mt][dt][r] * inv;
        if (fix && mt == 1 && quad == 3 && r == 3)  // s == 2047
          val = Vsum[dt][r] * (1.0f / 2048.0f);
        vals[rowoff + dt * 16 + l15] = f2bf(val);
      }
    }
}

// ---------------------------------------------------------------------------
// ws (64 MB): qh[0,8) kh[8,16) vth[16,24) vals[24,32)
// wqh[48,54) wql[54,60) woh[60,62) wol[62,64).
// d_out: xh[0,8) (dead after gemm_qkv); gemm_out2 writes final fp32 directly.
// ---------------------------------------------------------------------------
extern "C" void kernel_launch(void* const* d_in, const int* in_sizes, int n_in,
                              void* d_out, int out_size, void* d_ws, size_t ws_size,
                              hipStream_t stream) {
  const float* x    = (const float*)d_in[0];
  const float* Wqkv = (const float*)d_in[1];
  const float* bqkv = (const float*)d_in[2];
  const float* Wout = (const float*)d_in[3];
  const float* bout = (const float*)d_in[4];
  float* out = (float*)d_out;
  char* wsb = (char*)d_ws;

  unsigned short* qhp  = (unsigned short*)d_ws;
  unsigned short* khp  = qhp + 1 * 4194304;
  unsigned short* vthp = qhp + 2 * 4194304;
  unsigned short* vals = qhp + 3 * 4194304;
  unsigned short* wqh  = (unsigned short*)(wsb + (48u << 20));
  unsigned short* wql  = (unsigned short*)(wsb + (54u << 20));
  unsigned short* woh  = (unsigned short*)(wsb + (60u << 20));
  unsigned short* wol  = (unsigned short*)(wsb + (62u << 20));
  unsigned short* xh   = (unsigned short*)d_out;

  dim3 blk(256);
  split_all<<<8192, blk, 0, stream>>>(x, xh, Wqkv, wqh, wql, Wout, woh, wol);
  gemm_qkv<<<dim3(32, 24), blk, 0, stream>>>(xh, wqh, wql, bqkv, qhp, khp, vthp);
  attn_pair<<<dim3(32, 16), blk, 0, stream>>>(qhp, khp, vthp, vals);
  gemm_out2<<<dim3(32, 16), blk, 0, stream>>>(vals, woh, wol, bout, out);
}

// Round 15
// 217.803 us; speedup vs baseline: 1.5171x; 1.0172x over previous
//
#include <hip/hip_runtime.h>
#include <hip/hip_bf16.h>
#include <math.h>

#define Bb 2
#define Ss 2048
#define Ee 1024
#define Hh 16
#define HDd 64
#define NEG_INF_F -1000000000.0f

typedef __attribute__((ext_vector_type(8))) short bfrag;     // 8 bf16
typedef __attribute__((ext_vector_type(4))) float ffrag;     // 16x16 C/D
typedef __attribute__((ext_vector_type(16))) float ffrag16;  // 32x32 C/D
typedef __attribute__((ext_vector_type(8))) unsigned short us8;

#define C1F 0.1803368801f  /* 0.125 * log2(e) — folded into Q at gemm_qkv */

// s_waitcnt immediates: vmcnt[3:0]|expcnt[6:4]|lgkmcnt[11:8]|vmcnt[5:4]<<14
// (expcnt=7, lgkmcnt=15 -> "ignore"), vmcnt = 4 / 0.
#define WAIT_VM4 0x0F74
#define WAIT_VM0 0x0F70

// ---- bf16 helpers ----------------------------------------------------------
__device__ __forceinline__ unsigned short f2bf(float x) {
  unsigned u = __float_as_uint(x);
  u += 0x7fffu + ((u >> 16) & 1u);
  return (unsigned short)(u >> 16);
}
__device__ __forceinline__ float bf2f(unsigned short h) {
  return __uint_as_float(((unsigned)h) << 16);
}

__device__ __forceinline__ void async_copy16(void* lds, const void* g) {
  __builtin_amdgcn_global_load_lds(
      (const __attribute__((address_space(1))) unsigned int*)g,
      (__attribute__((address_space(3))) unsigned int*)lds, 16, 0, 0);
}

// ---------------------------------------------------------------------------
// Fused split pass: x (4M) -> hi only; Wqkv (3M), Wout (1M) -> hi/lo.
// ---------------------------------------------------------------------------
__global__ __launch_bounds__(256) void split_all(
    const float* __restrict__ x, unsigned short* __restrict__ xh,
    const float* __restrict__ wq, unsigned short* __restrict__ wqh,
    unsigned short* __restrict__ wql,
    const float* __restrict__ wo, unsigned short* __restrict__ woh,
    unsigned short* __restrict__ wol) {
  int bid = blockIdx.x;
  const float* in;
  unsigned short *hi, *lo;
  if (bid < 4096) { in = x; hi = xh; lo = nullptr; }
  else if (bid < 7168) { bid -= 4096; in = wq; hi = wqh; lo = wql; }
  else { bid -= 7168; in = wo; hi = woh; lo = wol; }
  const int idx = (bid * 256 + threadIdx.x) * 4;
  const float4 v = *(const float4*)(in + idx);
  unsigned short h0 = f2bf(v.x), h1 = f2bf(v.y), h2 = f2bf(v.z), h3 = f2bf(v.w);
  ushort4 hv = {h0, h1, h2, h3};
  *(ushort4*)(hi + idx) = hv;
  if (lo) {
    ushort4 lv = {f2bf(v.x - bf2f(h0)), f2bf(v.y - bf2f(h1)),
                  f2bf(v.z - bf2f(h2)), f2bf(v.w - bf2f(h3))};
    *(ushort4*)(lo + idx) = lv;
  }
}

// ---------------------------------------------------------------------------
// LDS slot map (rows of 32 bf16 = 4 x 16B chunks):
// slot(row,q) = (row>>1)*8 + ((((row&1)*4)|q) ^ ((row>>1)&7)).
// ---------------------------------------------------------------------------
__device__ __forceinline__ int gemm_slot(int row, int q) {
  return (row >> 1) * 8 + ((((row & 1) * 4) | q) ^ ((row >> 1) & 7));
}
__device__ __forceinline__ int slot_src_off(int slot, int ld) {
  const int dr = slot >> 3;
  const int idx8 = (slot & 7) ^ (dr & 7);
  const int row = dr * 2 + (idx8 >> 2);
  const int q = idx8 & 3;
  return row * ld + q * 8;
}

// ---------------------------------------------------------------------------
// QKV GEMM, 32x32x16 core: C = xh * (Wh + Wl)^T + bias (2 MFMAs/product).
// 128x128 tile. Epilogue (all single bf16): Q pre-scaled by C1F -> [bh][s][64];
// K -> [bh][s][64]; V^T -> [bh][d][s].
// ---------------------------------------------------------------------------
__global__ __launch_bounds__(256) void gemm_qkv(
    const unsigned short* __restrict__ Ah,
    const unsigned short* __restrict__ Bh, const unsigned short* __restrict__ Bl,
    const float* __restrict__ bias,
    unsigned short* __restrict__ q_h, unsigned short* __restrict__ k_h,
    unsigned short* __restrict__ vt_h) {
  __shared__ unsigned short sm[3 * 4096];
  const int tid = threadIdx.x;
  const int lane = tid & 63;
  const int w = tid >> 6;
  const int wm = w >> 1;
  const int wn = w & 1;
  const int l31 = lane & 31;
  const int e = lane >> 5;
  const int m0 = blockIdx.x * 128;
  const int n0 = blockIdx.y * 128;

  int coff[2], ldsb[2];
#pragma unroll
  for (int u = 0; u < 2; ++u) {
    const int slot = w * 128 + u * 64 + lane;
    coff[u] = slot_src_off(slot, 1024);
    ldsb[u] = (w * 128 + u * 64) * 8;
  }
  const unsigned short* srcs[3] = {
      Ah + (size_t)m0 * 1024, Bh + (size_t)n0 * 1024, Bl + (size_t)n0 * 1024};

  ffrag16 acc[2][2];
#pragma unroll
  for (int i = 0; i < 2; ++i)
#pragma unroll
    for (int j = 0; j < 2; ++j) acc[i][j] = (ffrag16)0.f;

  int ca[2][2], cb[2][2];
#pragma unroll
  for (int t = 0; t < 2; ++t)
#pragma unroll
    for (int h2 = 0; h2 < 2; ++h2) {
      ca[t][h2] = gemm_slot(wm * 64 + t * 32 + l31, h2 * 2 + e) * 8;
      cb[t][h2] = gemm_slot(wn * 64 + t * 32 + l31, h2 * 2 + e) * 8;
    }

  for (int k0 = 0; k0 < 1024; k0 += 32) {
    __syncthreads();
#pragma unroll
    for (int t = 0; t < 3; ++t)
#pragma unroll
      for (int u = 0; u < 2; ++u)
        async_copy16(&sm[t * 4096 + ldsb[u]], srcs[t] + coff[u] + k0);
    __syncthreads();

    bfrag ah[2][2], bhf[2][2], blf[2][2];
#pragma unroll
    for (int t = 0; t < 2; ++t)
#pragma unroll
      for (int h2 = 0; h2 < 2; ++h2) {
        ah[t][h2] = *(const bfrag*)&sm[0 * 4096 + ca[t][h2]];
        bhf[t][h2] = *(const bfrag*)&sm[1 * 4096 + cb[t][h2]];
        blf[t][h2] = *(const bfrag*)&sm[2 * 4096 + cb[t][h2]];
      }
#pragma unroll
    for (int mt = 0; mt < 2; ++mt)
#pragma unroll
      for (int nt = 0; nt < 2; ++nt)
#pragma unroll
        for (int h2 = 0; h2 < 2; ++h2) {
          acc[mt][nt] = __builtin_amdgcn_mfma_f32_32x32x16_bf16(
              ah[mt][h2], bhf[nt][h2], acc[mt][nt], 0, 0, 0);
          acc[mt][nt] = __builtin_amdgcn_mfma_f32_32x32x16_bf16(
              ah[mt][h2], blf[nt][h2], acc[mt][nt], 0, 0, 0);
        }
  }

#pragma unroll
  for (int nt = 0; nt < 2; ++nt) {
    const int n = n0 + wn * 64 + nt * 32 + l31;
    const float bv = bias[n];
    const int h = n / 192;
    const int c = n - h * 192;
    const int d = c & 63;
#pragma unroll
    for (int mt = 0; mt < 2; ++mt) {
      if (c >= 128) {
#pragma unroll
        for (int g = 0; g < 4; ++g) {
          const int m = m0 + wm * 64 + mt * 32 + g * 8 + e * 4;
          const int bidx = m >> 11;
          const int s = m & 2047;
          ushort4 hv4;
          unsigned short* ph = (unsigned short*)&hv4;
#pragma unroll
          for (int r = 0; r < 4; ++r)
            ph[r] = f2bf(acc[mt][nt][g * 4 + r] + bv);
          const size_t off =
              (size_t)(bidx * 16 + h) * (64 * 2048) + (size_t)d * 2048 + s;
          *(ushort4*)(vt_h + off) = hv4;
        }
      } else {
        const float scale = (c < 64) ? C1F : 1.0f;
        unsigned short* dh = (c < 64) ? q_h : k_h;
#pragma unroll
        for (int g = 0; g < 4; ++g)
#pragma unroll
          for (int r = 0; r < 4; ++r) {
            const int m = m0 + wm * 64 + mt * 32 + g * 8 + e * 4 + r;
            const int bidx = m >> 11;
            const int s = m & 2047;
            const size_t off =
                (size_t)(bidx * 16 + h) * (2048 * 64) + (size_t)s * 64 + d;
            dh[off] = f2bf((acc[mt][nt][g * 4 + r] + bv) * scale);
          }
      }
    }
  }
}

// ---------------------------------------------------------------------------
// Out-proj GEMM: A = vals single bf16, B = Wout hi/lo (2 MFMAs/product).
// 128x64 tile, 512 blocks. Writes fp32+bias directly to out.
// ---------------------------------------------------------------------------
__global__ __launch_bounds__(256) void gemm_out2(
    const unsigned short* __restrict__ A,
    const unsigned short* __restrict__ Bh, const unsigned short* __restrict__ Bl,
    const float* __restrict__ bias, float* __restrict__ out) {
  __shared__ unsigned short sm[8192];
  const int tid = threadIdx.x;
  const int lane = tid & 63;
  const int w = tid >> 6;
  const int wm = w >> 1;
  const int wn = w & 1;
  const int l31 = lane & 31;
  const int e = lane >> 5;
  const int m0 = blockIdx.x * 128;
  const int n0 = blockIdx.y * 64;

  int acoff[2], aldsb[2];
#pragma unroll
  for (int u = 0; u < 2; ++u) {
    const int slot = w * 128 + u * 64 + lane;
    acoff[u] = slot_src_off(slot, 1024);
    aldsb[u] = (w * 128 + u * 64) * 8;
  }
  const int bslot = w * 64 + lane;
  const int bcoff = slot_src_off(bslot, 1024);
  const int bldsb = bslot * 8;

  const unsigned short* Ap  = A + (size_t)m0 * 1024;
  const unsigned short* Bph = Bh + (size_t)n0 * 1024;
  const unsigned short* Bpl = Bl + (size_t)n0 * 1024;

  ffrag16 acc[2];
  acc[0] = (ffrag16)0.f;
  acc[1] = (ffrag16)0.f;

  int ca[2][2], cb[2];
#pragma unroll
  for (int t = 0; t < 2; ++t)
#pragma unroll
    for (int h2 = 0; h2 < 2; ++h2)
      ca[t][h2] = gemm_slot(wm * 64 + t * 32 + l31, h2 * 2 + e) * 8;
#pragma unroll
  for (int h2 = 0; h2 < 2; ++h2)
    cb[h2] = gemm_slot(wn * 32 + l31, h2 * 2 + e) * 8;

  for (int k0 = 0; k0 < 1024; k0 += 32) {
    __syncthreads();
#pragma unroll
    for (int u = 0; u < 2; ++u)
      async_copy16(&sm[0 + aldsb[u]], Ap + acoff[u] + k0);
    async_copy16(&sm[4096 + bldsb], Bph + bcoff + k0);
    async_copy16(&sm[6144 + bldsb], Bpl + bcoff + k0);
    __syncthreads();

    bfrag ah[2][2], bhf[2], blf[2];
#pragma unroll
    for (int t = 0; t < 2; ++t)
#pragma unroll
      for (int h2 = 0; h2 < 2; ++h2)
        ah[t][h2] = *(const bfrag*)&sm[0 + ca[t][h2]];
#pragma unroll
    for (int h2 = 0; h2 < 2; ++h2) {
      bhf[h2] = *(const bfrag*)&sm[4096 + cb[h2]];
      blf[h2] = *(const bfrag*)&sm[6144 + cb[h2]];
    }
#pragma unroll
    for (int mt = 0; mt < 2; ++mt)
#pragma unroll
      for (int h2 = 0; h2 < 2; ++h2) {
        acc[mt] = __builtin_amdgcn_mfma_f32_32x32x16_bf16(
            ah[mt][h2], bhf[h2], acc[mt], 0, 0, 0);
        acc[mt] = __builtin_amdgcn_mfma_f32_32x32x16_bf16(
            ah[mt][h2], blf[h2], acc[mt], 0, 0, 0);
      }
  }

  const int n = n0 + wn * 32 + l31;
  const float bv = bias[n];
#pragma unroll
  for (int mt = 0; mt < 2; ++mt)
#pragma unroll
    for (int g = 0; g < 4; ++g)
#pragma unroll
      for (int r = 0; r < 4; ++r) {
        const int m = m0 + wm * 64 + mt * 32 + g * 8 + e * 4 + r;
        out[(size_t)m * 1024 + n] = acc[mt][g * 4 + r] + bv;
      }
}

// ---------------------------------------------------------------------------
// Balanced MFMA flash attention — TRIPLE-buffered, raw-barrier pipeline.
// __syncthreads' implicit vmcnt(0) drained the prefetch DMA every iteration
// (~400+ cyc stall: compute iter ~500 cyc < HBM latency ~900 cyc). Replaced
// with: s_waitcnt vmcnt(4) (wait own-wave oldest 4 = tile kt's DMA, issued
// TWO iters ago) + raw s_barrier + sched_barrier(0), prefetch distance 2.
// Each wave issues exactly 4 DMAs/tile in order; barrier transitively covers
// all waves' staging. DMA(kt+2) targets the buffer last read in iter kt-1,
// sealed by this barrier. P region is wave-local (no barrier needed).
// LDS: 3 x 16KB stages + 16KB P = 64KB -> 2 blocks/CU.
// Math identical to R14 (fixed-max softmax, all-single-bf16, ones-MFMA l,
// fused row-2047 fixup).
// ---------------------------------------------------------------------------
__global__ __launch_bounds__(256) void attn_pair(
    const unsigned short* __restrict__ qh, const unsigned short* __restrict__ kh,
    const unsigned short* __restrict__ vth, unsigned short* __restrict__ vals) {
  __shared__ unsigned short sm[3 * 8192 + 8192];  // 3 stage sets + P
  const int tid = threadIdx.x;
  const int lane = tid & 63;
  const int w = tid >> 6;
  const int l15 = lane & 15;
  const int quad = lane >> 4;
  const int bh = blockIdx.x;
  const int y = blockIdx.y;
  const int rbase[2] = {64 * y + 16 * w, 64 * (31 - y) + 16 * w};
  const int ktB = 31 - y;
  const bool fix = (y == 0) && (w == 3);  // owns row 2047; sees all keys
  const size_t base = (size_t)bh * (Ss * HDd);
  const int PB = 24576;  // P region base (shorts)

  bfrag Qh[2][2];
#pragma unroll
  for (int mt = 0; mt < 2; ++mt)
#pragma unroll
    for (int ks = 0; ks < 2; ++ks) {
      const size_t off = base + (size_t)(rbase[mt] + l15) * 64 + ks * 32 + quad * 8;
      Qh[mt][ks] = *(const bfrag*)(qh + off);
    }

  bfrag vone;
#pragma unroll
  for (int j = 0; j < 8; ++j) vone[j] = (short)0x3F80;  // bf16 1.0

  const int c0 = w * 128 + lane;
  const int c1 = c0 + 64;
  const int r0 = c0 >> 3, r1 = c1 >> 3;
  const int s0 = ((c0 & 7) ^ (r0 & 7)) * 8;
  const int s1 = ((c1 & 7) ^ (r1 & 7)) * 8;
  const int koff0 = r0 * 64 + s0, koff1 = r1 * 64 + s1;
  const int voff0 = r0 * 2048 + s0, voff1 = r1 * 2048 + s1;
  const int ldsc0 = (w * 128) * 8;
  const int ldsc1 = (w * 128 + 64) * 8;

  ffrag O[2][4], Oe[2], Vsum[4];
#pragma unroll
  for (int mt = 0; mt < 2; ++mt) {
#pragma unroll
    for (int dt = 0; dt < 4; ++dt) O[mt][dt] = (ffrag)0.f;
    Oe[mt] = (ffrag)0.f;
  }
#pragma unroll
  for (int dt = 0; dt < 4; ++dt) Vsum[dt] = (ffrag)0.f;

  // prologue: stage tiles y -> set0, y+1 -> set1 (y<=15 so y+1 always valid).
  // Per wave: exactly 4 ordered DMAs per tile (2 K + 2 V).
  {
    const unsigned short* kph = kh + base + y * 4096;
    const unsigned short* vph = vth + base + y * 64;
    async_copy16(&sm[0 + ldsc0], kph + koff0);
    async_copy16(&sm[0 + ldsc1], kph + koff1);
    async_copy16(&sm[4096 + ldsc0], vph + voff0);
    async_copy16(&sm[4096 + ldsc1], vph + voff1);
    const unsigned short* kph1 = kh + base + (y + 1) * 4096;
    const unsigned short* vph1 = vth + base + (y + 1) * 64;
    async_copy16(&sm[8192 + 0 + ldsc0], kph1 + koff0);
    async_copy16(&sm[8192 + 0 + ldsc1], kph1 + koff1);
    async_copy16(&sm[8192 + 4096 + ldsc0], vph1 + voff0);
    async_copy16(&sm[8192 + 4096 + ldsc1], vph1 + voff1);
  }

  int b0 = 0, b1 = 8192, b2 = 16384;  // cur / next / prefetch-target (shorts)
  for (int kt = y; kt < 32; ++kt) {
    // wait own-wave DMA for tile kt (oldest 4), keep kt+1's 4 in flight
    if (kt + 1 < 32) __builtin_amdgcn_s_waitcnt(WAIT_VM4);
    else             __builtin_amdgcn_s_waitcnt(WAIT_VM0);
    __builtin_amdgcn_s_barrier();
    __builtin_amdgcn_sched_barrier(0);
    if (kt + 2 < 32) {  // prefetch distance 2
      const unsigned short* kph = kh + base + (kt + 2) * 4096;
      const unsigned short* vph = vth + base + (kt + 2) * 64;
      async_copy16(&sm[b2 + 0 + ldsc0], kph + koff0);
      async_copy16(&sm[b2 + 0 + ldsc1], kph + koff1);
      async_copy16(&sm[b2 + 4096 + ldsc0], vph + voff0);
      async_copy16(&sm[b2 + 4096 + ldsc1], vph + voff1);
    }
    const bool bact = (kt >= ktB);

    // ---- S = Q K^T (Q pre-scaled; K single bf16)
    ffrag S[2][4];
#pragma unroll
    for (int mt = 0; mt < 2; ++mt)
#pragma unroll
      for (int nt = 0; nt < 4; ++nt) S[mt][nt] = (ffrag)0.f;
#pragma unroll
    for (int nt = 0; nt < 4; ++nt) {
      const int krow = nt * 16 + l15;
#pragma unroll
      for (int ks = 0; ks < 2; ++ks) {
        const int koffr = b0 + krow * 64 + ((ks * 4 + quad) ^ (krow & 7)) * 8;
        const bfrag kbh = *(const bfrag*)&sm[koffr];
        S[0][nt] = __builtin_amdgcn_mfma_f32_16x16x32_bf16(Qh[0][ks], kbh, S[0][nt], 0, 0, 0);
        if (bact)
          S[1][nt] = __builtin_amdgcn_mfma_f32_16x16x32_bf16(Qh[1][ks], kbh, S[1][nt], 0, 0, 0);
      }
    }

    // ---- p = exp2(S [+ CM if masked]); packed bf16 cvt; store to P LDS
    const float CM = -1.442695041e9f;  // -1e9 * log2(e)
#pragma unroll
    for (int mt = 0; mt < 2; ++mt) {
      if (mt == 1 && !bact) continue;
      const bool partial = (kt == (mt == 0 ? y : ktB));
#pragma unroll
      for (int nt = 0; nt < 4; ++nt) {
        const int key = nt * 16 + l15;
#pragma unroll
        for (int rp = 0; rp < 2; ++rp) {
          float t0 = S[mt][nt][2 * rp];
          float t1 = S[mt][nt][2 * rp + 1];
          if (partial) {
            const int jg = kt * 64 + key;
            const int ig = rbase[mt] + quad * 4 + 2 * rp;
            if (jg <= ig) t0 += CM;
            if (jg <= ig + 1) t1 += CM;
          }
          float2 pf;
          pf.x = __builtin_amdgcn_exp2f(t0);
          pf.y = __builtin_amdgcn_exp2f(t1);
          const __hip_bfloat162 pb = __float22bfloat162_rn(pf);
          const unsigned short* pbs = (const unsigned short*)&pb;
          const int prow0 = w * 32 + mt * 16 + quad * 4 + 2 * rp;
          sm[PB + prow0 * 64 + (((key >> 3) ^ (prow0 & 7)) * 8 + (key & 7))] = pbs[0];
          const int prow1 = prow0 + 1;
          sm[PB + prow1 * 64 + (((key >> 3) ^ (prow1 & 7)) * 8 + (key & 7))] = pbs[1];
        }
      }
    }

    // ---- PV (V single) + l via ones-MFMA (+ Vsum on the fix wave)
#pragma unroll
    for (int ks = 0; ks < 2; ++ks) {
      bfrag pA[2];
#pragma unroll
      for (int mt = 0; mt < 2; ++mt) {
        if (mt == 1 && !bact) continue;
        const int prow = w * 32 + mt * 16 + l15;
        pA[mt] = *(const bfrag*)&sm[PB + prow * 64 + ((ks * 4 + quad) ^ (prow & 7)) * 8];
      }
      Oe[0] = __builtin_amdgcn_mfma_f32_16x16x32_bf16(pA[0], vone, Oe[0], 0, 0, 0);
      if (bact)
        Oe[1] = __builtin_amdgcn_mfma_f32_16x16x32_bf16(pA[1], vone, Oe[1], 0, 0, 0);
#pragma unroll
      for (int dt = 0; dt < 4; ++dt) {
        const int vrow = dt * 16 + l15;
        const int voffr = b0 + 4096 + vrow * 64 + ((ks * 4 + quad) ^ (vrow & 7)) * 8;
        const bfrag vbh = *(const bfrag*)&sm[voffr];
        O[0][dt] = __builtin_amdgcn_mfma_f32_16x16x32_bf16(pA[0], vbh, O[0][dt], 0, 0, 0);
        if (bact)
          O[1][dt] = __builtin_amdgcn_mfma_f32_16x16x32_bf16(pA[1], vbh, O[1][dt], 0, 0, 0);
        if (fix)
          Vsum[dt] = __builtin_amdgcn_mfma_f32_16x16x32_bf16(vone, vbh, Vsum[dt], 0, 0, 0);
      }
    }
    const int t = b0; b0 = b1; b1 = b2; b2 = t;  // rotate buffers
  }

  // ---- epilogue: vals[b][s][h*64+d] single bf16; l = Oe row sum.
  // Row 2047 (fully masked -> exactly uniform) = mean(V), from Vsum.
  const int b = bh >> 4;
  const int h = bh & 15;
#pragma unroll
  for (int mt = 0; mt < 2; ++mt)
#pragma unroll
    for (int r = 0; r < 4; ++r) {
      const float inv = 1.0f / Oe[mt][r];
      const int s = rbase[mt] + quad * 4 + r;
      const size_t rowoff = ((size_t)b * 2048 + s) * 1024 + h * 64;
#pragma unroll
      for (int dt = 0; dt < 4; ++dt) {
        float val = O[mt][dt][r] * inv;
        if (fix && mt == 1 && quad == 3 && r == 3)  // s == 2047
          val = Vsum[dt][r] * (1.0f / 2048.0f);
        vals[rowoff + dt * 16 + l15] = f2bf(val);
      }
    }
}

// ---------------------------------------------------------------------------
// ws (64 MB): qh[0,8) kh[8,16) vth[16,24) vals[24,32)
// wqh[48,54) wql[54,60) woh[60,62) wol[62,64).
// d_out: xh[0,8) (dead after gemm_qkv); gemm_out2 writes final fp32 directly.
// ---------------------------------------------------------------------------
extern "C" void kernel_launch(void* const* d_in, const int* in_sizes, int n_in,
                              void* d_out, int out_size, void* d_ws, size_t ws_size,
                              hipStream_t stream) {
  const float* x    = (const float*)d_in[0];
  const float* Wqkv = (const float*)d_in[1];
  const float* bqkv = (const float*)d_in[2];
  const float* Wout = (const float*)d_in[3];
  const float* bout = (const float*)d_in[4];
  float* out = (float*)d_out;
  char* wsb = (char*)d_ws;

  unsigned short* qhp  = (unsigned short*)d_ws;
  unsigned short* khp  = qhp + 1 * 4194304;
  unsigned short* vthp = qhp + 2 * 4194304;
  unsigned short* vals = qhp + 3 * 4194304;
  unsigned short* wqh  = (unsigned short*)(wsb + (48u << 20));
  unsigned short* wql  = (unsigned short*)(wsb + (54u << 20));
  unsigned short* woh  = (unsigned short*)(wsb + (60u << 20));
  unsigned short* wol  = (unsigned short*)(wsb + (62u << 20));
  unsigned short* xh   = (unsigned short*)d_out;

  dim3 blk(256);
  split_all<<<8192, blk, 0, stream>>>(x, xh, Wqkv, wqh, wql, Wout, woh, wol);
  gemm_qkv<<<dim3(32, 24), blk, 0, stream>>>(xh, wqh, wql, bqkv, qhp, khp, vthp);
  attn_pair<<<dim3(32, 16), blk, 0, stream>>>(qhp, khp, vthp, vals);
  gemm_out2<<<dim3(32, 16), blk, 0, stream>>>(vals, woh, wol, bout, out);
}